// Round 15
// baseline (1416.864 us; speedup 1.0000x reference)
//
#include <hip/hip_runtime.h>

// GCN: 7x GCNConv (first 6 with ReLU+BN training-mode), then global_add_pool.
// N=16384 nodes, E=131072 edges, 64 graphs. fp32 in/out, fp16 internal + MFMA.
// agg on the narrow side per layer (agg is linear).
// BN: explicit fused stats->apply (a,b inline from s1/s2). W-fold abandoned
// (R4/R11). Safe folds: BN4 -> L5 agg (inline), BN6 -> GEMV (inline).
// L1/L5 stats fused into GEMM epilogue. GEMM: 256x256, rotation swizzle
// (conflicts=0), 2 barriers/kt, R15: fragment ping-pong - ds_reads issued one
// phase ahead into the idle register set so LDS hides under 32-MFMA clusters;
// vmcnt(4) at BOTH barriers (FIFO proof in round log).

#define NN 16384
#define NE 131072
#define NG 64

typedef unsigned int u32;
typedef unsigned short u16;
typedef __attribute__((ext_vector_type(8))) _Float16 half8;
typedef __attribute__((ext_vector_type(4))) float f32x4;
typedef __attribute__((ext_vector_type(8))) u16 us8;
typedef __attribute__((ext_vector_type(4))) u16 us4;
typedef __attribute__((ext_vector_type(2))) u16 us2;

#define AS1(p) ((const __attribute__((address_space(1))) void*)(p))
#define AS3(p) ((__attribute__((address_space(3))) void*)(p))

__device__ __forceinline__ float b2f(u16 h) {
    _Float16 x = __builtin_bit_cast(_Float16, h);
    return (float)x;
}
__device__ __forceinline__ u16 f2b(float f) {
    _Float16 x = (_Float16)f;
    return __builtin_bit_cast(u16, x);
}

template <int VW> struct VecU;
template <> struct VecU<8> { typedef us8 T; };
template <> struct VecU<4> { typedef us4 T; };
template <> struct VecU<2> { typedef us2 T; };
template <> struct VecU<1> { typedef u16 T; };

template <int VW>
__device__ __forceinline__ void loadf(const u16* p, float* f) {
    typename VecU<VW>::T v = *(const typename VecU<VW>::T*)p;
    if constexpr (VW == 1) {
        f[0] = b2f((u16)v);
    } else {
        #pragma unroll
        for (int j = 0; j < VW; ++j) f[j] = b2f(v[j]);
    }
}
template <int VW>
__device__ __forceinline__ void storef(u16* p, const float* f) {
    typename VecU<VW>::T v;
    if constexpr (VW == 1) {
        v = f2b(f[0]);
    } else {
        #pragma unroll
        for (int j = 0; j < VW; ++j) v[j] = f2b(f[j]);
    }
    *(typename VecU<VW>::T*)p = v;
}

// BN affine from stats: a = g*rsqrt(var+eps), b = be - m*a
__device__ __forceinline__ void bn_ab(float s1c, float s2c, float gc, float bec,
                                      float& a, float& b) {
    float m = s1c * (1.f / NN);
    float var = s2c * (1.f / NN) - m * m;
    a = gc * rsqrtf(var + 1e-5f);
    b = bec - m * a;
}

// ---------- graph prep ----------
__global__ void k_degi(const int* __restrict__ dst, int* __restrict__ deg) {
    int e = blockIdx.x * 256 + threadIdx.x;
    if (e < NE) atomicAdd(&deg[dst[e]], 1);
}
__global__ void k_nrm(const int* __restrict__ src, const int* __restrict__ dst,
                      const float* __restrict__ dinv, float* __restrict__ nrm) {
    int e = blockIdx.x * 256 + threadIdx.x;
    if (e < NE) nrm[e] = dinv[src[e]] * dinv[dst[e]];
}
// scan over degrees -> rowptr; also writes dinv = rsqrt(deg+1)
__global__ __launch_bounds__(1024) void k_scan(const int* __restrict__ deg, int* __restrict__ rowptr,
                                               float* __restrict__ dinv) {
    __shared__ int part[1024];
    int t = threadIdx.x;
    int base = t * 16;
    int s = 0;
    #pragma unroll
    for (int j = 0; j < 16; ++j) {
        int d = deg[base + j];
        dinv[base + j] = rsqrtf((float)(d + 1));   // +1 self loop
        s += d;
    }
    part[t] = s;
    __syncthreads();
    for (int off = 1; off < 1024; off <<= 1) {
        int v = 0;
        if (t >= off) v = part[t - off];
        __syncthreads();
        part[t] += v;
        __syncthreads();
    }
    int run = part[t] - s;  // exclusive prefix
    for (int j = 0; j < 16; ++j) { rowptr[base + j] = run; run += deg[base + j]; }
    if (t == 1023) rowptr[NN] = run;
}
__global__ void k_place(const int* __restrict__ src, const int* __restrict__ dst,
                        const float* __restrict__ nrm, const int* __restrict__ rowptr,
                        int* __restrict__ cursor, int* __restrict__ csr_src,
                        float* __restrict__ csr_w) {
    int e = blockIdx.x * 256 + threadIdx.x;
    if (e >= NE) return;
    int d = dst[e];
    int p = rowptr[d] + atomicAdd(&cursor[d], 1);
    csr_src[p] = src[e];
    csr_w[p] = nrm[e];
}

// ---------- conversions ----------
// x (NN x 396 f32) -> xpad (NN x 512 f16), vectorized us8 stores
__global__ void k_x2b(const float* __restrict__ x, u16* __restrict__ xp) {
    int idx = blockIdx.x * 256 + threadIdx.x;   // over NN*64
    int i = idx >> 6, cg = idx & 63;
    int c0 = cg * 8;
    float v[8];
    #pragma unroll
    for (int j = 0; j < 8; ++j) {
        int c = c0 + j;
        v[j] = (c < 396) ? x[(size_t)i * 396 + c] : 0.f;
    }
    storef<8>(xp + (size_t)i * 512 + c0, v);
}
// Wt[n][k] = f16(W[k][n]), K padded with zeros
__global__ void k_wt(const float* __restrict__ W, u16* __restrict__ Wt,
                     int Ksrc, int Kpad, int N) {
    __shared__ float t[32][33];
    int k0 = blockIdx.x * 32, n0 = blockIdx.y * 32;
    int tx = threadIdx.x, ty = threadIdx.y;
    #pragma unroll
    for (int j = 0; j < 4; ++j) {
        int k = k0 + ty + j * 8;
        float v = 0.f;
        if (k < Ksrc) v = W[(size_t)k * N + n0 + tx];
        t[ty + j * 8][tx] = v;
    }
    __syncthreads();
    #pragma unroll
    for (int j = 0; j < 4; ++j) {
        int n = n0 + ty + j * 8;
        int k = k0 + tx;
        Wt[(size_t)n * Kpad + k] = f2b(t[tx][ty + j * 8]);
    }
}

// ---------- CSR gather aggregation (one block per node, F/VW threads) ----------
// mode 0: out = acc
// mode 1: out = relu(acc + bias[c])
// mode 2: out = a[c]*acc + s_i*b[c], a,b inline from s1/s2/g/be
// svw non-null: thread 0 also writes svec[i] = dinv_i^2 + sum(w) (agg row-sum).
template <int VW>
__global__ __launch_bounds__(256) void k_agg(const u16* __restrict__ in, u16* __restrict__ out,
                                             const int* __restrict__ rowptr,
                                             const int* __restrict__ csr_src,
                                             const float* __restrict__ csr_w,
                                             const float* __restrict__ dinv,
                                             const float* __restrict__ svec,
                                             const float* __restrict__ bias,
                                             const float* __restrict__ s1,
                                             const float* __restrict__ s2,
                                             const float* __restrict__ g,
                                             const float* __restrict__ be,
                                             float* __restrict__ svw,
                                             int F, int mode) {
    int i = blockIdx.x;
    int c0 = threadIdx.x * VW;
    float acc[VW];
    float d2 = dinv[i]; d2 *= d2;
    float wsum = d2;
    {
        float v[VW];
        loadf<VW>(in + (size_t)i * F + c0, v);
        #pragma unroll
        for (int j = 0; j < VW; ++j) acc[j] = d2 * v[j];
    }
    int r0 = rowptr[i], r1 = rowptr[i + 1];
    int e = r0;
    if (r1 - r0 >= 2) {                 // dual-accumulator ILP
        float acc2[VW];
        #pragma unroll
        for (int j = 0; j < VW; ++j) acc2[j] = 0.f;
        for (; e + 1 < r1; e += 2) {
            int sa = csr_src[e], sb = csr_src[e + 1];
            float wa = csr_w[e], wb = csr_w[e + 1];
            wsum += wa + wb;
            float va[VW], vb[VW];
            loadf<VW>(in + (size_t)sa * F + c0, va);
            loadf<VW>(in + (size_t)sb * F + c0, vb);
            #pragma unroll
            for (int j = 0; j < VW; ++j) { acc[j] += wa * va[j]; acc2[j] += wb * vb[j]; }
        }
        #pragma unroll
        for (int j = 0; j < VW; ++j) acc[j] += acc2[j];
    }
    for (; e < r1; ++e) {
        int s = csr_src[e];
        float w = csr_w[e];
        wsum += w;
        float v[VW];
        loadf<VW>(in + (size_t)s * F + c0, v);
        #pragma unroll
        for (int j = 0; j < VW; ++j) acc[j] += w * v[j];
    }
    if (mode == 1) {
        #pragma unroll
        for (int j = 0; j < VW; ++j) acc[j] = fmaxf(acc[j] + bias[c0 + j], 0.f);
    } else if (mode == 2) {
        float si = svec[i];
        #pragma unroll
        for (int j = 0; j < VW; ++j) {
            float a, b;
            bn_ab(s1[c0 + j], s2[c0 + j], g[c0 + j], be[c0 + j], a, b);
            acc[j] = a * acc[j] + si * b;
        }
    }
    storef<VW>(out + (size_t)i * F + c0, acc);
    if (svw && threadIdx.x == 0) svw[i] = wsum;
}

// ---------- BN stats (for agg-output layers); block = F/VW threads ----------
#define SROWS 128
template <int VW>
__global__ __launch_bounds__(256) void k_stats(const u16* __restrict__ h, float* __restrict__ s1,
                                               float* __restrict__ s2, int F) {
    int c0 = threadIdx.x * VW;
    int r0 = blockIdx.y * SROWS;
    float s[VW], q[VW];
    #pragma unroll
    for (int j = 0; j < VW; ++j) { s[j] = 0.f; q[j] = 0.f; }
    for (int r = r0; r < r0 + SROWS; ++r) {
        float v[VW];
        loadf<VW>(h + (size_t)r * F + c0, v);
        #pragma unroll
        for (int j = 0; j < VW; ++j) { s[j] += v[j]; q[j] += v[j] * v[j]; }
    }
    #pragma unroll
    for (int j = 0; j < VW; ++j) {
        atomicAdd(&s1[c0 + j], s[j]);
        atomicAdd(&s2[c0 + j], q[j]);
    }
}
// fused stats->affine apply: h = a*(h-m)+be, a,b computed per-thread from s1/s2
__global__ __launch_bounds__(256) void k_bnapply(u16* __restrict__ h, const float* __restrict__ s1,
                                                 const float* __restrict__ s2,
                                                 const float* __restrict__ g,
                                                 const float* __restrict__ be, int F) {
    size_t idx = blockIdx.x * (size_t)256 + threadIdx.x;
    int Fv = F >> 3;
    int c = (int)(idx % Fv) * 8;
    u16* p = h + idx * 8;
    float v[8];
    loadf<8>(p, v);
    #pragma unroll
    for (int j = 0; j < 8; ++j) {
        float a, b;
        bn_ab(s1[c + j], s2[c + j], g[c + j], be[c + j], a, b);
        v[j] = a * v[j] + b;
    }
    storef<8>(p, v);
}

// ================= 256x256 MFMA GEMM (f16), ping-pong fragments =================
// C[M,N] = A[M,K] @ Wt[N,K]^T. 512 thr = 8 waves (2 Mx4 N), BK=64,
// LDS 128 KiB: A[2buf][2Khalf][16KiB] @0, B same @64KiB.
// Rotation perm (conflict-free): granule c of row r at LDS granule (c+(r>>1))&3.
// Per kt: ph0 {stage h1(kt+1), read SB<-(buf,kk1), 32 MFMA on SA} vmcnt(4) BAR
//         ph1 {stage h0(kt+2), read SA<-(buf^1,kk0 of kt+1), 32 MFMA on SB}
//         vmcnt(4) BAR
// mid vmcnt(4) retires h0(kt+1) (needed by ph1's read); end vmcnt(4) retires
// h1(kt+1) (needed by ph0(kt+1)'s read). All LDS write/read pairs >=2 barriers
// apart (slot-by-slot proof in round log). ds_reads issue one phase ahead ->
// compiler's counted lgkmcnt lets LDS hide under the MFMA cluster.
__device__ __forceinline__ void stage16k(const char* gbase, size_t rs, int ktile, int h,
                                         char* slot, int tid) {
    size_t colb = (size_t)ktile * 128 + h * 64;
    #pragma unroll
    for (int i = 0; i < 2; ++i) {
        int G = i * 512 + tid;
        int r = G >> 2;
        int c = ((G & 3) - (r >> 1)) & 3;   // inverse of storage rotation
        __builtin_amdgcn_global_load_lds(AS1(gbase + (size_t)r * rs + colb + c * 16),
                                         AS3(slot + i * 8192 + ((tid >> 6) << 10)), 16, 0, 0);
    }
}

__global__ __launch_bounds__(512, 2) void k_gemm256(const u16* __restrict__ A,
                                                    const u16* __restrict__ Wt,
                                                    const float* __restrict__ bias,
                                                    u16* __restrict__ C,
                                                    float* __restrict__ s1,
                                                    float* __restrict__ s2,
                                                    int K, int N, int bx, int fuse) {
    extern __shared__ __align__(16) char smem[];
    int nwg = gridDim.x;
    int chunk = nwg >> 3;
    int swz = (blockIdx.x & 7) * chunk + (blockIdx.x >> 3);
    int tx = swz % bx, ty = swz / bx;
    int tid = threadIdx.x;
    int wid = tid >> 6, lane = tid & 63;
    int wr = wid >> 2, wc = wid & 3;         // 2 x 4 wave grid
    int lo = lane & 15, hi = lane >> 4;
    int sw = (((hi + (lo >> 1)) & 3) << 4);  // rotation swizzle (conflict-free)
    size_t row0 = (size_t)ty * 256;
    size_t col0 = (size_t)tx * 256;
    int nkt = K >> 6;

    const char* gA = (const char*)(A + row0 * K);
    const char* gB = (const char*)(Wt + col0 * K);
    size_t rs = (size_t)K * 2;

    const char* aA = smem + wr * 8192 + lo * 64 + sw;
    const char* bA = smem + 65536 + wc * 4096 + lo * 64 + sw;
#define ASL(b, h) (smem + (((b) * 2 + (h)) << 14))
#define BSL(b, h) (smem + 65536 + (((b) * 2 + (h)) << 14))

    f32x4 acc[8][4];
    #pragma unroll
    for (int m = 0; m < 8; ++m)
        #pragma unroll
        for (int n = 0; n < 4; ++n) acc[m][n] = {0.f, 0.f, 0.f, 0.f};
    half8 af0A[4], af1A[4], bfA[4];          // fragment set A
    half8 af0B[4], af1B[4], bfB[4];          // fragment set B

    // ---- prologue: kt0 fully + kt1 h0 ----
    stage16k(gA, rs, 0, 0, ASL(0, 0), tid);
    stage16k(gB, rs, 0, 0, BSL(0, 0), tid);
    stage16k(gA, rs, 0, 1, ASL(0, 1), tid);
    stage16k(gB, rs, 0, 1, BSL(0, 1), tid);
    stage16k(gA, rs, 1, 0, ASL(1, 0), tid);
    stage16k(gB, rs, 1, 0, BSL(1, 0), tid);
    asm volatile("s_waitcnt vmcnt(4)" ::: "memory");
    __builtin_amdgcn_sched_barrier(0);
    __builtin_amdgcn_s_barrier();

#define READ_FRAGS(S, BUF, KK)                                                             \
    {                                                                                      \
        _Pragma("unroll") for (int j = 0; j < 4; ++j)                                      \
            af0##S[j] = *(const half8*)(aA + (BUF) * 32768 + (KK) * 16384 + j * 1024);     \
        _Pragma("unroll") for (int j = 0; j < 4; ++j)                                      \
            af1##S[j] = *(const half8*)(aA + (BUF) * 32768 + (KK) * 16384 + 4096 + j * 1024); \
        _Pragma("unroll") for (int j = 0; j < 4; ++j)                                      \
            bf##S[j] = *(const half8*)(bA + (BUF) * 32768 + (KK) * 16384 + j * 1024);      \
    }
#define MFMA_SET(S)                                                                        \
    {                                                                                      \
        __builtin_amdgcn_s_setprio(1);                                                     \
        _Pragma("unroll") for (int j = 0; j < 4; ++j)                                      \
            _Pragma("unroll") for (int n = 0; n < 4; ++n)                                  \
                acc[j][n] = __builtin_amdgcn_mfma_f32_16x16x32_f16(                        \
                    af0##S[j], bf##S[n], acc[j][n], 0, 0, 0);                              \
        _Pragma("unroll") for (int j = 0; j < 4; ++j)                                      \
            _Pragma("unroll") for (int n = 0; n < 4; ++n)                                  \
                acc[4 + j][n] = __builtin_amdgcn_mfma_f32_16x16x32_f16(                    \
                    af1##S[j], bf##S[n], acc[4 + j][n], 0, 0, 0);                          \
        __builtin_amdgcn_s_setprio(0);                                                     \
    }
#define SYNC_POINT                                                                         \
    {                                                                                      \
        asm volatile("s_waitcnt vmcnt(4)" ::: "memory");                                   \
        __builtin_amdgcn_sched_barrier(0);                                                 \
        __builtin_amdgcn_s_barrier();                                                      \
    }

    // preload set A = kk0 fragments of kt0
    READ_FRAGS(A, 0, 0);

    for (int kt = 0; kt < nkt; ++kt) {
        int buf = kt & 1;
        // ph0: stage h1(kt+1) -> buf^1 ; prefetch SB <- (buf, kk=1) ; MFMA on SA
        if (kt + 1 < nkt) {
            stage16k(gA, rs, kt + 1, 1, ASL(buf ^ 1, 1), tid);
            stage16k(gB, rs, kt + 1, 1, BSL(buf ^ 1, 1), tid);
        }
        READ_FRAGS(B, buf, 1);
        MFMA_SET(A);
        SYNC_POINT;   // mid: retires h0(kt+1)
        // ph1: stage h0(kt+2) -> buf ; prefetch SA <- (buf^1, kk=0) [kt+1] ; MFMA on SB
        if (kt + 2 < nkt) {
            stage16k(gA, rs, kt + 2, 0, ASL(buf, 0), tid);
            stage16k(gB, rs, kt + 2, 0, BSL(buf, 0), tid);
        }
        READ_FRAGS(A, buf ^ 1, 0);
        MFMA_SET(B);
        SYNC_POINT;   // end: retires h1(kt+1)
    }

    // ---- epilogue (+ optional fused column stats) ----
    float cs[4] = {0.f, 0.f, 0.f, 0.f}, cq[4] = {0.f, 0.f, 0.f, 0.f};
    #pragma unroll
    for (int fm = 0; fm < 8; ++fm) {
        #pragma unroll
        for (int n = 0; n < 4; ++n) {
            #pragma unroll
            for (int r = 0; r < 4; ++r) {
                size_t row = row0 + wr * 128 + fm * 16 + hi * 4 + r;
                size_t col = col0 + wc * 64 + n * 16 + lo;
                float v = acc[fm][n][r];
                if (fuse) v = fmaxf(v + bias[col], 0.f);
                C[row * N + col] = f2b(v);
                cs[n] += v;
                cq[n] += v * v;
            }
        }
    }
    if (s1) {
        asm volatile("s_waitcnt vmcnt(0)" ::: "memory");
        __syncthreads();
        float* sp = (float*)smem;        // 512 floats: [localcol][0]=sum,[1]=sumsq
        sp[tid] = 0.f;
        __syncthreads();
        #pragma unroll
        for (int n = 0; n < 4; ++n) {
            int lc = wc * 64 + n * 16 + lo;
            atomicAdd(&sp[lc * 2], cs[n]);
            atomicAdd(&sp[lc * 2 + 1], cq[n]);
        }
        __syncthreads();
        if (tid < 256) {
            atomicAdd(&s1[col0 + tid], sp[tid * 2]);
            atomicAdd(&s2[col0 + tid], sp[tid * 2 + 1]);
        }
    }
#undef READ_FRAGS
#undef MFMA_SET
#undef SYNC_POINT
#undef ASL
#undef BSL
}

// ---------- 128x128 m97-style GEMM (kept for N=256 layer) ----------
__global__ __launch_bounds__(256) void k_gemm(const u16* __restrict__ A, const u16* __restrict__ Wt,
                                              const float* __restrict__ bias, u16* __restrict__ C,
                                              int K, int N, int bx, int fuse) {
    __shared__ __align__(16) u16 As[128 * 32];
    __shared__ __align__(16) u16 Bs[128 * 32];
    int nwg = gridDim.x;
    int chunk = nwg >> 3;
    int swz = (blockIdx.x & 7) * chunk + (blockIdx.x >> 3);
    int tx = swz % bx, ty = swz / bx;
    int tid = threadIdx.x;
    int wid = tid >> 6, lane = tid & 63;
    int wr = wid >> 1, wc = wid & 1;
    int lo = lane & 15, hi = lane >> 4;
    size_t row0 = (size_t)ty * 128;
    size_t col0 = (size_t)tx * 128;

    f32x4 acc[4][4];
    #pragma unroll
    for (int m = 0; m < 4; ++m)
        #pragma unroll
        for (int n = 0; n < 4; ++n) acc[m][n] = {0.f, 0.f, 0.f, 0.f};

    const char* gA = (const char*)(A + row0 * K);
    const char* gB = (const char*)(Wt + col0 * K);
    size_t rs = (size_t)K * 2;
    int lin0 = tid * 16;
    int lin1 = lin0 + 4096;
    int rA0 = lin0 >> 6, cb0 = lin0 & 63;
    int rA1 = lin1 >> 6, cb1 = lin1 & 63;
    unsigned ldsOff = (unsigned)(wid << 10);

    for (int k0 = 0; k0 < K; k0 += 32) {
        __syncthreads();
        size_t kb = (size_t)k0 * 2;
        __builtin_amdgcn_global_load_lds(AS1(gA + (size_t)rA0 * rs + cb0 + kb),
                                         AS3((char*)As + ldsOff), 16, 0, 0);
        __builtin_amdgcn_global_load_lds(AS1(gA + (size_t)rA1 * rs + cb1 + kb),
                                         AS3((char*)As + 4096 + ldsOff), 16, 0, 0);
        __builtin_amdgcn_global_load_lds(AS1(gB + (size_t)rA0 * rs + cb0 + kb),
                                         AS3((char*)Bs + ldsOff), 16, 0, 0);
        __builtin_amdgcn_global_load_lds(AS1(gB + (size_t)rA1 * rs + cb1 + kb),
                                         AS3((char*)Bs + 4096 + ldsOff), 16, 0, 0);
        __syncthreads();
        half8 afr[4], bfr[4];
        #pragma unroll
        for (int m = 0; m < 4; ++m)
            afr[m] = *(const half8*)((const u16*)As + (wr * 64 + m * 16 + lo) * 32 + hi * 8);
        #pragma unroll
        for (int n = 0; n < 4; ++n)
            bfr[n] = *(const half8*)((const u16*)Bs + (wc * 64 + n * 16 + lo) * 32 + hi * 8);
        #pragma unroll
        for (int m = 0; m < 4; ++m)
            #pragma unroll
            for (int n = 0; n < 4; ++n)
                acc[m][n] = __builtin_amdgcn_mfma_f32_16x16x32_f16(afr[m], bfr[n], acc[m][n], 0, 0, 0);
    }
    #pragma unroll
    for (int m = 0; m < 4; ++m) {
        #pragma unroll
        for (int n = 0; n < 4; ++n) {
            #pragma unroll
            for (int r = 0; r < 4; ++r) {
                size_t row = row0 + wr * 64 + m * 16 + hi * 4 + r;
                size_t col = col0 + wc * 64 + n * 16 + lo;
                float v = acc[m][n][r];
                if (fuse) v = fmaxf(v + bias[col], 0.f);
                C[row * N + col] = f2b(v);
            }
        }
    }
}

// ---------- layer 7: fused BN6 + GEMV (a,b inline from s1/s2) ----------
__global__ __launch_bounds__(256) void k_gemv(const u16* __restrict__ A, const float* __restrict__ w,
                                              const float* __restrict__ s1, const float* __restrict__ s2,
                                              const float* __restrict__ g, const float* __restrict__ be,
                                              float* __restrict__ y) {
    int row = blockIdx.x * 4 + (threadIdx.x >> 6);
    int lane = threadIdx.x & 63;
    const u16* h = A + (size_t)row * 256;
    float s = 0.f;
    #pragma unroll
    for (int j = 0; j < 4; ++j) {
        int c = lane + j * 64;
        float a, b;
        bn_ab(s1[c], s2[c], g[c], be[c], a, b);
        s += (a * b2f(h[c]) + b) * w[c];
    }
    #pragma unroll
    for (int off = 32; off; off >>= 1) s += __shfl_down(s, off);
    if (lane == 0) y[row] = s;
}
__global__ void k_final(const float* __restrict__ y, const int* __restrict__ rowptr,
                        const int* __restrict__ csr_src, const float* __restrict__ csr_w,
                        const float* __restrict__ dinv, const int* __restrict__ batch,
                        const float* __restrict__ b7, float* __restrict__ out) {
    int i = blockIdx.x * 256 + threadIdx.x;
    if (i >= NN) return;
    float v = dinv[i] * dinv[i] * y[i];
    int r1 = rowptr[i + 1];
    for (int e = rowptr[i]; e < r1; ++e) v += csr_w[e] * y[csr_src[e]];
    atomicAdd(&out[batch[i]], v + b7[0]);
}
__global__ void k_sentinel(float* out, float v) {
    if (threadIdx.x == 0 && blockIdx.x == 0) out[0] = v;
}

// ---------- host ----------
static inline char* alignp(char* p) { return (char*)(((uintptr_t)p + 255) & ~(uintptr_t)255); }

extern "C" void kernel_launch(void* const* d_in, const int* in_sizes, int n_in,
                              void* d_out, int out_size, void* d_ws, size_t ws_size,
                              hipStream_t stream) {
    const float* x = (const float*)d_in[0];
    const int* ei = (const int*)d_in[1];
    const int* src = ei;
    const int* dst = ei + NE;
    const int* batch = (const int*)d_in[2];
    const float* W[7]; const float* bv[7];
    for (int i = 0; i < 7; ++i) { W[i] = (const float*)d_in[3 + 2 * i]; bv[i] = (const float*)d_in[4 + 2 * i]; }
    const float* g[6]; const float* be[6];
    for (int i = 0; i < 6; ++i) { g[i] = (const float*)d_in[17 + 2 * i]; be[i] = (const float*)d_in[18 + 2 * i]; }
    float* out = (float*)d_out;

    // workspace layout
    char* p = (char*)d_ws;
    u16* Abuf = (u16*)p; p += (size_t)NN * 4096 * 2;
    u16* Bbuf = (u16*)p; p += (size_t)NN * 2048 * 2;
    u16* xpad = (u16*)p; p += (size_t)NN * 512 * 2;
    u16* W1t = (u16*)p; p += (size_t)4096 * 512 * 2;
    u16* W2t = (u16*)p; p += (size_t)2048 * 4096 * 2;
    u16* W3t = (u16*)p; p += (size_t)1024 * 2048 * 2;
    u16* W4t = (u16*)p; p += (size_t)1024 * 1024 * 2;
    u16* W5t = (u16*)p; p += (size_t)2048 * 1024 * 2;
    u16* W6t = (u16*)p; p += (size_t)256 * 2048 * 2;
    p = alignp(p);
    int* degi = (int*)p; p += NN * 4;
    int* cursor = (int*)p; p += NN * 4;
    int* rowptr = (int*)p; p += (NN + 1) * 4; p = alignp(p);
    int* csr_src = (int*)p; p += NE * 4;
    float* csr_w = (float*)p; p += NE * 4;
    float* dinv = (float*)p; p += NN * 4;
    float* nrm = (float*)p; p += NE * 4;
    float* svec = (float*)p; p += NN * 4;
    float* s1 = (float*)p; p += 4096 * 4;
    float* s2 = (float*)p; p += 4096 * 4;
    float* y = (float*)p; p += NN * 4;
    size_t need = (size_t)(p - (char*)d_ws);
    if (need > ws_size) {
        hipMemsetAsync(d_out, 0, NG * sizeof(float), stream);
        k_sentinel<<<1, 64, 0, stream>>>(out, (float)(ws_size >> 20));
        return;
    }

    (void)hipFuncSetAttribute((const void*)k_gemm256,
                              hipFuncAttributeMaxDynamicSharedMemorySize, 131072);

    // --- graph prep ---
    hipMemsetAsync(degi, 0, 2 * NN * sizeof(int), stream);  // degi + cursor
    k_degi<<<NE / 256, 256, 0, stream>>>(dst, degi);
    k_scan<<<1, 1024, 0, stream>>>(degi, rowptr, dinv);     // rowptr + dinv
    k_nrm<<<NE / 256, 256, 0, stream>>>(src, dst, dinv, nrm);
    k_place<<<NE / 256, 256, 0, stream>>>(src, dst, nrm, rowptr, cursor, csr_src, csr_w);

    // --- conversions (all weights plain f16 transpose) ---
    k_x2b<<<(NN * 64) / 256, 256, 0, stream>>>(x, xpad);
    dim3 wtb(32, 8);
    k_wt<<<dim3(16, 128), wtb, 0, stream>>>(W[0], W1t, 396, 512, 4096);
    k_wt<<<dim3(128, 64), wtb, 0, stream>>>(W[1], W2t, 4096, 4096, 2048);
    k_wt<<<dim3(64, 32), wtb, 0, stream>>>(W[2], W3t, 2048, 2048, 1024);
    k_wt<<<dim3(32, 32), wtb, 0, stream>>>(W[3], W4t, 1024, 1024, 1024);
    k_wt<<<dim3(32, 64), wtb, 0, stream>>>(W[4], W5t, 1024, 1024, 2048);
    k_wt<<<dim3(64, 8), wtb, 0, stream>>>(W[5], W6t, 2048, 2048, 256);

    auto gemm256 = [&](const u16* A, const u16* Wt, const float* bias, u16* Cp,
                       float* st1, float* st2, int K, int N, int fuse) {
        int bx = N / 256;
        k_gemm256<<<bx * (NN / 256), 512, 131072, stream>>>(A, Wt, bias, Cp, st1, st2, K, N, bx, fuse);
    };
    auto agg = [&](const u16* in, u16* o, const float* bias, int li, float* svw,
                   int F, int mode) {
        const float* gp = (mode == 2) ? g[li] : nullptr;
        const float* bep = (mode == 2) ? be[li] : nullptr;
        if (F >= 512) k_agg<8><<<NN, F / 8, 0, stream>>>(in, o, rowptr, csr_src, csr_w, dinv, svec, bias, s1, s2, gp, bep, svw, F, mode);
        else k_agg<4><<<NN, F / 4, 0, stream>>>(in, o, rowptr, csr_src, csr_w, dinv, svec, bias, s1, s2, gp, bep, svw, F, mode);
    };
    auto stats = [&](const u16* h, int F) {
        hipMemsetAsync(s1, 0, 2 * 4096 * sizeof(float), stream);   // s1+s2 (contiguous)
        if (F >= 512) k_stats<8><<<dim3(1, NN / SROWS), F / 8, 0, stream>>>(h, s1, s2, F);
        else k_stats<4><<<dim3(1, NN / SROWS), F / 4, 0, stream>>>(h, s1, s2, F);
    };
    auto bnapply = [&](u16* h, int F, int li) {
        k_bnapply<<<(int)(((size_t)NN * F / 8) / 256), 256, 0, stream>>>(h, s1, s2, g[li], be[li], F);
    };

    // --- L1: 396(512) -> 4096, agg-first (writes svec); stats fused; BN1 applied ---
    agg(xpad, Bbuf, nullptr, 0, svec, 512, 0);
    hipMemsetAsync(s1, 0, 2 * 4096 * sizeof(float), stream);
    gemm256(Bbuf, W1t, bv[0], Abuf, s1, s2, 512, 4096, 1);
    bnapply(Abuf, 4096, 0);

    // --- L2: 4096 -> 2048, gemm-first; BN2 applied ---
    gemm256(Abuf, W2t, nullptr, Bbuf, nullptr, nullptr, 4096, 2048, 0);
    agg(Bbuf, Abuf, bv[1], 1, nullptr, 2048, 1);
    stats(Abuf, 2048);
    bnapply(Abuf, 2048, 1);

    // --- L3: 2048 -> 1024, gemm-first; BN3 applied ---
    gemm256(Abuf, W3t, nullptr, Bbuf, nullptr, nullptr, 2048, 1024, 0);
    agg(Bbuf, Abuf, bv[2], 2, nullptr, 1024, 1);
    stats(Abuf, 1024);
    bnapply(Abuf, 1024, 2);

    // --- L4: 1024 -> 1024, gemm-first; BN4 unapplied (inline-folded into L5 agg) ---
    gemm256(Abuf, W4t, nullptr, Bbuf, nullptr, nullptr, 1024, 1024, 0);
    agg(Bbuf, Abuf, bv[3], 3, nullptr, 1024, 1);
    stats(Abuf, 1024);                                      // BN4 stats -> s1,s2

    // --- L5: 1024 -> 2048, agg-first, BN4 a,b inline (mode 2); stats fused; BN5 applied ---
    agg(Abuf, Bbuf, nullptr, 3, nullptr, 1024, 2);
    hipMemsetAsync(s1, 0, 2 * 4096 * sizeof(float), stream);
    gemm256(Bbuf, W5t, bv[4], Abuf, s1, s2, 1024, 2048, 1);
    bnapply(Abuf, 2048, 4);

    // --- L6: 2048 -> 256 (128^2 GEMM); BN6 unapplied (inline-folded into GEMV) ---
    k_gemm<<<(256 / 128) * (NN / 128), 256, 0, stream>>>(Abuf, W6t, nullptr, Bbuf, 2048, 256, 256 / 128, 0);
    agg(Bbuf, Abuf, bv[5], 5, nullptr, 256, 1);
    stats(Abuf, 256);                                       // BN6 stats -> s1,s2

    // --- L7: 256 -> 1 with BN6 inline in GEMV, then agg + pool ---
    k_gemv<<<NN / 4, 256, 0, stream>>>(Abuf, W[6], s1, s2, g[5], be[5], y);
    hipMemsetAsync(d_out, 0, NG * sizeof(float), stream);
    k_final<<<NN / 256, 256, 0, stream>>>(y, rowptr, csr_src, csr_w, dinv, batch, bv[6], out);
}

// Round 17
// 1405.496 us; speedup vs baseline: 1.0081x; 1.0081x over previous
//
#include <hip/hip_runtime.h>

// GCN: 7x GCNConv (first 6 with ReLU+BN training-mode), then global_add_pool.
// N=16384 nodes, E=131072 edges, 64 graphs. fp32 in/out, fp16 internal + MFMA.
// agg on the narrow side per layer (agg is linear).
// BN: explicit fused stats->apply (a,b inline from s1/s2). W-fold abandoned
// (R4/R11). Safe folds: BN4 -> L5 agg (inline), BN6 -> GEMV (inline).
// L1/L5 stats fused into GEMM epilogue. GEMM: 256x256, rotation swizzle
// (conflicts=0), TWO barriers per K-tile, 32-MFMA clusters (R14-measured best:
// 245us/1122TF; R15 ping-pong regression reverted - compiler's counted lgkmcnt
// already overlaps ds_reads with MFMAs, extra frag set only added VGPR pressure).

#define NN 16384
#define NE 131072
#define NG 64

typedef unsigned int u32;
typedef unsigned short u16;
typedef __attribute__((ext_vector_type(8))) _Float16 half8;
typedef __attribute__((ext_vector_type(4))) float f32x4;
typedef __attribute__((ext_vector_type(8))) u16 us8;
typedef __attribute__((ext_vector_type(4))) u16 us4;
typedef __attribute__((ext_vector_type(2))) u16 us2;

#define AS1(p) ((const __attribute__((address_space(1))) void*)(p))
#define AS3(p) ((__attribute__((address_space(3))) void*)(p))

__device__ __forceinline__ float b2f(u16 h) {
    _Float16 x = __builtin_bit_cast(_Float16, h);
    return (float)x;
}
__device__ __forceinline__ u16 f2b(float f) {
    _Float16 x = (_Float16)f;
    return __builtin_bit_cast(u16, x);
}

template <int VW> struct VecU;
template <> struct VecU<8> { typedef us8 T; };
template <> struct VecU<4> { typedef us4 T; };
template <> struct VecU<2> { typedef us2 T; };
template <> struct VecU<1> { typedef u16 T; };

template <int VW>
__device__ __forceinline__ void loadf(const u16* p, float* f) {
    typename VecU<VW>::T v = *(const typename VecU<VW>::T*)p;
    if constexpr (VW == 1) {
        f[0] = b2f((u16)v);
    } else {
        #pragma unroll
        for (int j = 0; j < VW; ++j) f[j] = b2f(v[j]);
    }
}
template <int VW>
__device__ __forceinline__ void storef(u16* p, const float* f) {
    typename VecU<VW>::T v;
    if constexpr (VW == 1) {
        v = f2b(f[0]);
    } else {
        #pragma unroll
        for (int j = 0; j < VW; ++j) v[j] = f2b(f[j]);
    }
    *(typename VecU<VW>::T*)p = v;
}

// BN affine from stats: a = g*rsqrt(var+eps), b = be - m*a
__device__ __forceinline__ void bn_ab(float s1c, float s2c, float gc, float bec,
                                      float& a, float& b) {
    float m = s1c * (1.f / NN);
    float var = s2c * (1.f / NN) - m * m;
    a = gc * rsqrtf(var + 1e-5f);
    b = bec - m * a;
}

// ---------- graph prep ----------
__global__ void k_degi(const int* __restrict__ dst, int* __restrict__ deg) {
    int e = blockIdx.x * 256 + threadIdx.x;
    if (e < NE) atomicAdd(&deg[dst[e]], 1);
}
__global__ void k_nrm(const int* __restrict__ src, const int* __restrict__ dst,
                      const float* __restrict__ dinv, float* __restrict__ nrm) {
    int e = blockIdx.x * 256 + threadIdx.x;
    if (e < NE) nrm[e] = dinv[src[e]] * dinv[dst[e]];
}
// scan over degrees -> rowptr; also writes dinv = rsqrt(deg+1)
__global__ __launch_bounds__(1024) void k_scan(const int* __restrict__ deg, int* __restrict__ rowptr,
                                               float* __restrict__ dinv) {
    __shared__ int part[1024];
    int t = threadIdx.x;
    int base = t * 16;
    int s = 0;
    #pragma unroll
    for (int j = 0; j < 16; ++j) {
        int d = deg[base + j];
        dinv[base + j] = rsqrtf((float)(d + 1));   // +1 self loop
        s += d;
    }
    part[t] = s;
    __syncthreads();
    for (int off = 1; off < 1024; off <<= 1) {
        int v = 0;
        if (t >= off) v = part[t - off];
        __syncthreads();
        part[t] += v;
        __syncthreads();
    }
    int run = part[t] - s;  // exclusive prefix
    for (int j = 0; j < 16; ++j) { rowptr[base + j] = run; run += deg[base + j]; }
    if (t == 1023) rowptr[NN] = run;
}
__global__ void k_place(const int* __restrict__ src, const int* __restrict__ dst,
                        const float* __restrict__ nrm, const int* __restrict__ rowptr,
                        int* __restrict__ cursor, int* __restrict__ csr_src,
                        float* __restrict__ csr_w) {
    int e = blockIdx.x * 256 + threadIdx.x;
    if (e >= NE) return;
    int d = dst[e];
    int p = rowptr[d] + atomicAdd(&cursor[d], 1);
    csr_src[p] = src[e];
    csr_w[p] = nrm[e];
}

// ---------- conversions ----------
// x (NN x 396 f32) -> xpad (NN x 512 f16), vectorized us8 stores
__global__ void k_x2b(const float* __restrict__ x, u16* __restrict__ xp) {
    int idx = blockIdx.x * 256 + threadIdx.x;   // over NN*64
    int i = idx >> 6, cg = idx & 63;
    int c0 = cg * 8;
    float v[8];
    #pragma unroll
    for (int j = 0; j < 8; ++j) {
        int c = c0 + j;
        v[j] = (c < 396) ? x[(size_t)i * 396 + c] : 0.f;
    }
    storef<8>(xp + (size_t)i * 512 + c0, v);
}
// Wt[n][k] = f16(W[k][n]), K padded with zeros
__global__ void k_wt(const float* __restrict__ W, u16* __restrict__ Wt,
                     int Ksrc, int Kpad, int N) {
    __shared__ float t[32][33];
    int k0 = blockIdx.x * 32, n0 = blockIdx.y * 32;
    int tx = threadIdx.x, ty = threadIdx.y;
    #pragma unroll
    for (int j = 0; j < 4; ++j) {
        int k = k0 + ty + j * 8;
        float v = 0.f;
        if (k < Ksrc) v = W[(size_t)k * N + n0 + tx];
        t[ty + j * 8][tx] = v;
    }
    __syncthreads();
    #pragma unroll
    for (int j = 0; j < 4; ++j) {
        int n = n0 + ty + j * 8;
        int k = k0 + tx;
        Wt[(size_t)n * Kpad + k] = f2b(t[tx][ty + j * 8]);
    }
}

// ---------- CSR gather aggregation (one block per node, F/VW threads) ----------
// mode 0: out = acc
// mode 1: out = relu(acc + bias[c])
// mode 2: out = a[c]*acc + s_i*b[c], a,b inline from s1/s2/g/be
// svw non-null: thread 0 also writes svec[i] = dinv_i^2 + sum(w) (agg row-sum).
template <int VW>
__global__ __launch_bounds__(256) void k_agg(const u16* __restrict__ in, u16* __restrict__ out,
                                             const int* __restrict__ rowptr,
                                             const int* __restrict__ csr_src,
                                             const float* __restrict__ csr_w,
                                             const float* __restrict__ dinv,
                                             const float* __restrict__ svec,
                                             const float* __restrict__ bias,
                                             const float* __restrict__ s1,
                                             const float* __restrict__ s2,
                                             const float* __restrict__ g,
                                             const float* __restrict__ be,
                                             float* __restrict__ svw,
                                             int F, int mode) {
    int i = blockIdx.x;
    int c0 = threadIdx.x * VW;
    float acc[VW];
    float d2 = dinv[i]; d2 *= d2;
    float wsum = d2;
    {
        float v[VW];
        loadf<VW>(in + (size_t)i * F + c0, v);
        #pragma unroll
        for (int j = 0; j < VW; ++j) acc[j] = d2 * v[j];
    }
    int r0 = rowptr[i], r1 = rowptr[i + 1];
    int e = r0;
    if (r1 - r0 >= 2) {                 // dual-accumulator ILP
        float acc2[VW];
        #pragma unroll
        for (int j = 0; j < VW; ++j) acc2[j] = 0.f;
        for (; e + 1 < r1; e += 2) {
            int sa = csr_src[e], sb = csr_src[e + 1];
            float wa = csr_w[e], wb = csr_w[e + 1];
            wsum += wa + wb;
            float va[VW], vb[VW];
            loadf<VW>(in + (size_t)sa * F + c0, va);
            loadf<VW>(in + (size_t)sb * F + c0, vb);
            #pragma unroll
            for (int j = 0; j < VW; ++j) { acc[j] += wa * va[j]; acc2[j] += wb * vb[j]; }
        }
        #pragma unroll
        for (int j = 0; j < VW; ++j) acc[j] += acc2[j];
    }
    for (; e < r1; ++e) {
        int s = csr_src[e];
        float w = csr_w[e];
        wsum += w;
        float v[VW];
        loadf<VW>(in + (size_t)s * F + c0, v);
        #pragma unroll
        for (int j = 0; j < VW; ++j) acc[j] += w * v[j];
    }
    if (mode == 1) {
        #pragma unroll
        for (int j = 0; j < VW; ++j) acc[j] = fmaxf(acc[j] + bias[c0 + j], 0.f);
    } else if (mode == 2) {
        float si = svec[i];
        #pragma unroll
        for (int j = 0; j < VW; ++j) {
            float a, b;
            bn_ab(s1[c0 + j], s2[c0 + j], g[c0 + j], be[c0 + j], a, b);
            acc[j] = a * acc[j] + si * b;
        }
    }
    storef<VW>(out + (size_t)i * F + c0, acc);
    if (svw && threadIdx.x == 0) svw[i] = wsum;
}

// ---------- BN stats (for agg-output layers); block = F/VW threads ----------
#define SROWS 128
template <int VW>
__global__ __launch_bounds__(256) void k_stats(const u16* __restrict__ h, float* __restrict__ s1,
                                               float* __restrict__ s2, int F) {
    int c0 = threadIdx.x * VW;
    int r0 = blockIdx.y * SROWS;
    float s[VW], q[VW];
    #pragma unroll
    for (int j = 0; j < VW; ++j) { s[j] = 0.f; q[j] = 0.f; }
    for (int r = r0; r < r0 + SROWS; ++r) {
        float v[VW];
        loadf<VW>(h + (size_t)r * F + c0, v);
        #pragma unroll
        for (int j = 0; j < VW; ++j) { s[j] += v[j]; q[j] += v[j] * v[j]; }
    }
    #pragma unroll
    for (int j = 0; j < VW; ++j) {
        atomicAdd(&s1[c0 + j], s[j]);
        atomicAdd(&s2[c0 + j], q[j]);
    }
}
// fused stats->affine apply: h = a*(h-m)+be, a,b computed per-thread from s1/s2
__global__ __launch_bounds__(256) void k_bnapply(u16* __restrict__ h, const float* __restrict__ s1,
                                                 const float* __restrict__ s2,
                                                 const float* __restrict__ g,
                                                 const float* __restrict__ be, int F) {
    size_t idx = blockIdx.x * (size_t)256 + threadIdx.x;
    int Fv = F >> 3;
    int c = (int)(idx % Fv) * 8;
    u16* p = h + idx * 8;
    float v[8];
    loadf<8>(p, v);
    #pragma unroll
    for (int j = 0; j < 8; ++j) {
        float a, b;
        bn_ab(s1[c + j], s2[c + j], g[c + j], be[c + j], a, b);
        v[j] = a * v[j] + b;
    }
    storef<8>(p, v);
}

// ================= 256x256 MFMA GEMM (f16), 2 barriers per K-tile =================
// C[M,N] = A[M,K] @ Wt[N,K]^T. 512 thr = 8 waves (2 Mx4 N), BK=64,
// LDS 128 KiB: A[2buf][2Khalf][16KiB] @0, B same @64KiB.
// Rotation perm (conflict-free): granule c of row r at LDS granule (c+(r>>1))&3.
// Per kt: ph0 {read kk=0 both mh (12 b128), stage h1(kt+1) A+B, 32 MFMA} BAR
//         ph1 {read kk=1 both mh, stage h0(kt+2) A+B, 32 MFMA, vmcnt(4)} BAR
// Hazards: (buf,0) written ph1, read ph0 -> mid barrier; (buf^1,1) written ph0,
// last read kt-1 ph1 -> end barrier. vmcnt(4)@kt-end retires ph0's 4 (h1(kt+1));
// ph1's 4 (h0(kt+2)) retire at (kt+1)-end. Both >=1 barrier before readers.
__device__ __forceinline__ void stage16k(const char* gbase, size_t rs, int ktile, int h,
                                         char* slot, int tid) {
    size_t colb = (size_t)ktile * 128 + h * 64;
    #pragma unroll
    for (int i = 0; i < 2; ++i) {
        int G = i * 512 + tid;
        int r = G >> 2;
        int c = ((G & 3) - (r >> 1)) & 3;   // inverse of storage rotation
        __builtin_amdgcn_global_load_lds(AS1(gbase + (size_t)r * rs + colb + c * 16),
                                         AS3(slot + i * 8192 + ((tid >> 6) << 10)), 16, 0, 0);
    }
}

__global__ __launch_bounds__(512, 2) void k_gemm256(const u16* __restrict__ A,
                                                    const u16* __restrict__ Wt,
                                                    const float* __restrict__ bias,
                                                    u16* __restrict__ C,
                                                    float* __restrict__ s1,
                                                    float* __restrict__ s2,
                                                    int K, int N, int bx, int fuse) {
    extern __shared__ __align__(16) char smem[];
    int nwg = gridDim.x;
    int chunk = nwg >> 3;
    int swz = (blockIdx.x & 7) * chunk + (blockIdx.x >> 3);
    int tx = swz % bx, ty = swz / bx;
    int tid = threadIdx.x;
    int wid = tid >> 6, lane = tid & 63;
    int wr = wid >> 2, wc = wid & 3;         // 2 x 4 wave grid
    int lo = lane & 15, hi = lane >> 4;
    int sw = (((hi + (lo >> 1)) & 3) << 4);  // rotation swizzle (conflict-free)
    size_t row0 = (size_t)ty * 256;
    size_t col0 = (size_t)tx * 256;
    int nkt = K >> 6;

    const char* gA = (const char*)(A + row0 * K);
    const char* gB = (const char*)(Wt + col0 * K);
    size_t rs = (size_t)K * 2;

    const char* aA = smem + wr * 8192 + lo * 64 + sw;
    const char* bA = smem + 65536 + wc * 4096 + lo * 64 + sw;
#define ASL(b, h) (smem + (((b) * 2 + (h)) << 14))
#define BSL(b, h) (smem + 65536 + (((b) * 2 + (h)) << 14))

    f32x4 acc[8][4];
    #pragma unroll
    for (int m = 0; m < 8; ++m)
        #pragma unroll
        for (int n = 0; n < 4; ++n) acc[m][n] = {0.f, 0.f, 0.f, 0.f};
    half8 af0[4], af1[4], bf[4];

    // ---- prologue: kt0 fully + kt1 h0 ----
    stage16k(gA, rs, 0, 0, ASL(0, 0), tid);
    stage16k(gB, rs, 0, 0, BSL(0, 0), tid);
    stage16k(gA, rs, 0, 1, ASL(0, 1), tid);
    stage16k(gB, rs, 0, 1, BSL(0, 1), tid);
    stage16k(gA, rs, 1, 0, ASL(1, 0), tid);
    stage16k(gB, rs, 1, 0, BSL(1, 0), tid);
    asm volatile("s_waitcnt vmcnt(4)" ::: "memory");
    __builtin_amdgcn_sched_barrier(0);
    __builtin_amdgcn_s_barrier();

#define DS_LOADS2(KK)                                                                      \
    {                                                                                      \
        _Pragma("unroll") for (int j = 0; j < 4; ++j)                                      \
            af0[j] = *(const half8*)(aA + buf * 32768 + (KK) * 16384 + j * 1024);          \
        _Pragma("unroll") for (int j = 0; j < 4; ++j)                                      \
            af1[j] = *(const half8*)(aA + buf * 32768 + (KK) * 16384 + 4096 + j * 1024);   \
        _Pragma("unroll") for (int j = 0; j < 4; ++j)                                      \
            bf[j] = *(const half8*)(bA + buf * 32768 + (KK) * 16384 + j * 1024);           \
    }
#define MFMA_BOTH                                                                          \
    {                                                                                      \
        __builtin_amdgcn_s_setprio(1);                                                     \
        _Pragma("unroll") for (int j = 0; j < 4; ++j)                                      \
            _Pragma("unroll") for (int n = 0; n < 4; ++n)                                  \
                acc[j][n] = __builtin_amdgcn_mfma_f32_16x16x32_f16(                        \
                    af0[j], bf[n], acc[j][n], 0, 0, 0);                                    \
        _Pragma("unroll") for (int j = 0; j < 4; ++j)                                      \
            _Pragma("unroll") for (int n = 0; n < 4; ++n)                                  \
                acc[4 + j][n] = __builtin_amdgcn_mfma_f32_16x16x32_f16(                    \
                    af1[j], bf[n], acc[4 + j][n], 0, 0, 0);                                \
        __builtin_amdgcn_s_setprio(0);                                                     \
    }
#define END_BARRIER                                                                        \
    {                                                                                      \
        asm volatile("" ::: "memory");                                                     \
        __builtin_amdgcn_s_barrier();                                                      \
    }

    for (int kt = 0; kt < nkt; ++kt) {
        int buf = kt & 1;
        // ph0: kk=0, all 8 fm ; stage h1(kt+1) -> buf^1
        DS_LOADS2(0);
        if (kt + 1 < nkt) {
            stage16k(gA, rs, kt + 1, 1, ASL(buf ^ 1, 1), tid);
            stage16k(gB, rs, kt + 1, 1, BSL(buf ^ 1, 1), tid);
        }
        MFMA_BOTH;
        END_BARRIER;
        // ph1: kk=1, all 8 fm ; stage h0(kt+2) -> buf ; counted vmcnt
        DS_LOADS2(1);
        if (kt + 2 < nkt) {
            stage16k(gA, rs, kt + 2, 0, ASL(buf, 0), tid);
            stage16k(gB, rs, kt + 2, 0, BSL(buf, 0), tid);
        }
        MFMA_BOTH;
        asm volatile("s_waitcnt vmcnt(4)" ::: "memory");
        __builtin_amdgcn_sched_barrier(0);
        END_BARRIER;
    }

    // ---- epilogue (+ optional fused column stats) ----
    float cs[4] = {0.f, 0.f, 0.f, 0.f}, cq[4] = {0.f, 0.f, 0.f, 0.f};
    #pragma unroll
    for (int fm = 0; fm < 8; ++fm) {
        #pragma unroll
        for (int n = 0; n < 4; ++n) {
            #pragma unroll
            for (int r = 0; r < 4; ++r) {
                size_t row = row0 + wr * 128 + fm * 16 + hi * 4 + r;
                size_t col = col0 + wc * 64 + n * 16 + lo;
                float v = acc[fm][n][r];
                if (fuse) v = fmaxf(v + bias[col], 0.f);
                C[row * N + col] = f2b(v);
                cs[n] += v;
                cq[n] += v * v;
            }
        }
    }
    if (s1) {
        asm volatile("s_waitcnt vmcnt(0)" ::: "memory");
        __syncthreads();
        float* sp = (float*)smem;        // 512 floats: [localcol][0]=sum,[1]=sumsq
        sp[tid] = 0.f;
        __syncthreads();
        #pragma unroll
        for (int n = 0; n < 4; ++n) {
            int lc = wc * 64 + n * 16 + lo;
            atomicAdd(&sp[lc * 2], cs[n]);
            atomicAdd(&sp[lc * 2 + 1], cq[n]);
        }
        __syncthreads();
        if (tid < 256) {
            atomicAdd(&s1[col0 + tid], sp[tid * 2]);
            atomicAdd(&s2[col0 + tid], sp[tid * 2 + 1]);
        }
    }
#undef DS_LOADS2
#undef MFMA_BOTH
#undef END_BARRIER
#undef ASL
#undef BSL
}

// ---------- 128x128 m97-style GEMM (kept for N=256 layer) ----------
__global__ __launch_bounds__(256) void k_gemm(const u16* __restrict__ A, const u16* __restrict__ Wt,
                                              const float* __restrict__ bias, u16* __restrict__ C,
                                              int K, int N, int bx, int fuse) {
    __shared__ __align__(16) u16 As[128 * 32];
    __shared__ __align__(16) u16 Bs[128 * 32];
    int nwg = gridDim.x;
    int chunk = nwg >> 3;
    int swz = (blockIdx.x & 7) * chunk + (blockIdx.x >> 3);
    int tx = swz % bx, ty = swz / bx;
    int tid = threadIdx.x;
    int wid = tid >> 6, lane = tid & 63;
    int wr = wid >> 1, wc = wid & 1;
    int lo = lane & 15, hi = lane >> 4;
    size_t row0 = (size_t)ty * 128;
    size_t col0 = (size_t)tx * 128;

    f32x4 acc[4][4];
    #pragma unroll
    for (int m = 0; m < 4; ++m)
        #pragma unroll
        for (int n = 0; n < 4; ++n) acc[m][n] = {0.f, 0.f, 0.f, 0.f};

    const char* gA = (const char*)(A + row0 * K);
    const char* gB = (const char*)(Wt + col0 * K);
    size_t rs = (size_t)K * 2;
    int lin0 = tid * 16;
    int lin1 = lin0 + 4096;
    int rA0 = lin0 >> 6, cb0 = lin0 & 63;
    int rA1 = lin1 >> 6, cb1 = lin1 & 63;
    unsigned ldsOff = (unsigned)(wid << 10);

    for (int k0 = 0; k0 < K; k0 += 32) {
        __syncthreads();
        size_t kb = (size_t)k0 * 2;
        __builtin_amdgcn_global_load_lds(AS1(gA + (size_t)rA0 * rs + cb0 + kb),
                                         AS3((char*)As + ldsOff), 16, 0, 0);
        __builtin_amdgcn_global_load_lds(AS1(gA + (size_t)rA1 * rs + cb1 + kb),
                                         AS3((char*)As + 4096 + ldsOff), 16, 0, 0);
        __builtin_amdgcn_global_load_lds(AS1(gB + (size_t)rA0 * rs + cb0 + kb),
                                         AS3((char*)Bs + ldsOff), 16, 0, 0);
        __builtin_amdgcn_global_load_lds(AS1(gB + (size_t)rA1 * rs + cb1 + kb),
                                         AS3((char*)Bs + 4096 + ldsOff), 16, 0, 0);
        __syncthreads();
        half8 afr[4], bfr[4];
        #pragma unroll
        for (int m = 0; m < 4; ++m)
            afr[m] = *(const half8*)((const u16*)As + (wr * 64 + m * 16 + lo) * 32 + hi * 8);
        #pragma unroll
        for (int n = 0; n < 4; ++n)
            bfr[n] = *(const half8*)((const u16*)Bs + (wc * 64 + n * 16 + lo) * 32 + hi * 8);
        #pragma unroll
        for (int m = 0; m < 4; ++m)
            #pragma unroll
            for (int n = 0; n < 4; ++n)
                acc[m][n] = __builtin_amdgcn_mfma_f32_16x16x32_f16(afr[m], bfr[n], acc[m][n], 0, 0, 0);
    }
    #pragma unroll
    for (int m = 0; m < 4; ++m) {
        #pragma unroll
        for (int n = 0; n < 4; ++n) {
            #pragma unroll
            for (int r = 0; r < 4; ++r) {
                size_t row = row0 + wr * 64 + m * 16 + hi * 4 + r;
                size_t col = col0 + wc * 64 + n * 16 + lo;
                float v = acc[m][n][r];
                if (fuse) v = fmaxf(v + bias[col], 0.f);
                C[row * N + col] = f2b(v);
            }
        }
    }
}

// ---------- layer 7: fused BN6 + GEMV (a,b inline from s1/s2) ----------
__global__ __launch_bounds__(256) void k_gemv(const u16* __restrict__ A, const float* __restrict__ w,
                                              const float* __restrict__ s1, const float* __restrict__ s2,
                                              const float* __restrict__ g, const float* __restrict__ be,
                                              float* __restrict__ y) {
    int row = blockIdx.x * 4 + (threadIdx.x >> 6);
    int lane = threadIdx.x & 63;
    const u16* h = A + (size_t)row * 256;
    float s = 0.f;
    #pragma unroll
    for (int j = 0; j < 4; ++j) {
        int c = lane + j * 64;
        float a, b;
        bn_ab(s1[c], s2[c], g[c], be[c], a, b);
        s += (a * b2f(h[c]) + b) * w[c];
    }
    #pragma unroll
    for (int off = 32; off; off >>= 1) s += __shfl_down(s, off);
    if (lane == 0) y[row] = s;
}
__global__ void k_final(const float* __restrict__ y, const int* __restrict__ rowptr,
                        const int* __restrict__ csr_src, const float* __restrict__ csr_w,
                        const float* __restrict__ dinv, const int* __restrict__ batch,
                        const float* __restrict__ b7, float* __restrict__ out) {
    int i = blockIdx.x * 256 + threadIdx.x;
    if (i >= NN) return;
    float v = dinv[i] * dinv[i] * y[i];
    int r1 = rowptr[i + 1];
    for (int e = rowptr[i]; e < r1; ++e) v += csr_w[e] * y[csr_src[e]];
    atomicAdd(&out[batch[i]], v + b7[0]);
}
__global__ void k_sentinel(float* out, float v) {
    if (threadIdx.x == 0 && blockIdx.x == 0) out[0] = v;
}

// ---------- host ----------
static inline char* alignp(char* p) { return (char*)(((uintptr_t)p + 255) & ~(uintptr_t)255); }

extern "C" void kernel_launch(void* const* d_in, const int* in_sizes, int n_in,
                              void* d_out, int out_size, void* d_ws, size_t ws_size,
                              hipStream_t stream) {
    const float* x = (const float*)d_in[0];
    const int* ei = (const int*)d_in[1];
    const int* src = ei;
    const int* dst = ei + NE;
    const int* batch = (const int*)d_in[2];
    const float* W[7]; const float* bv[7];
    for (int i = 0; i < 7; ++i) { W[i] = (const float*)d_in[3 + 2 * i]; bv[i] = (const float*)d_in[4 + 2 * i]; }
    const float* g[6]; const float* be[6];
    for (int i = 0; i < 6; ++i) { g[i] = (const float*)d_in[17 + 2 * i]; be[i] = (const float*)d_in[18 + 2 * i]; }
    float* out = (float*)d_out;

    // workspace layout
    char* p = (char*)d_ws;
    u16* Abuf = (u16*)p; p += (size_t)NN * 4096 * 2;
    u16* Bbuf = (u16*)p; p += (size_t)NN * 2048 * 2;
    u16* xpad = (u16*)p; p += (size_t)NN * 512 * 2;
    u16* W1t = (u16*)p; p += (size_t)4096 * 512 * 2;
    u16* W2t = (u16*)p; p += (size_t)2048 * 4096 * 2;
    u16* W3t = (u16*)p; p += (size_t)1024 * 2048 * 2;
    u16* W4t = (u16*)p; p += (size_t)1024 * 1024 * 2;
    u16* W5t = (u16*)p; p += (size_t)2048 * 1024 * 2;
    u16* W6t = (u16*)p; p += (size_t)256 * 2048 * 2;
    p = alignp(p);
    int* degi = (int*)p; p += NN * 4;
    int* cursor = (int*)p; p += NN * 4;
    int* rowptr = (int*)p; p += (NN + 1) * 4; p = alignp(p);
    int* csr_src = (int*)p; p += NE * 4;
    float* csr_w = (float*)p; p += NE * 4;
    float* dinv = (float*)p; p += NN * 4;
    float* nrm = (float*)p; p += NE * 4;
    float* svec = (float*)p; p += NN * 4;
    float* s1 = (float*)p; p += 4096 * 4;
    float* s2 = (float*)p; p += 4096 * 4;
    float* y = (float*)p; p += NN * 4;
    size_t need = (size_t)(p - (char*)d_ws);
    if (need > ws_size) {
        hipMemsetAsync(d_out, 0, NG * sizeof(float), stream);
        k_sentinel<<<1, 64, 0, stream>>>(out, (float)(ws_size >> 20));
        return;
    }

    (void)hipFuncSetAttribute((const void*)k_gemm256,
                              hipFuncAttributeMaxDynamicSharedMemorySize, 131072);

    // --- graph prep ---
    hipMemsetAsync(degi, 0, 2 * NN * sizeof(int), stream);  // degi + cursor
    k_degi<<<NE / 256, 256, 0, stream>>>(dst, degi);
    k_scan<<<1, 1024, 0, stream>>>(degi, rowptr, dinv);     // rowptr + dinv
    k_nrm<<<NE / 256, 256, 0, stream>>>(src, dst, dinv, nrm);
    k_place<<<NE / 256, 256, 0, stream>>>(src, dst, nrm, rowptr, cursor, csr_src, csr_w);

    // --- conversions (all weights plain f16 transpose) ---
    k_x2b<<<(NN * 64) / 256, 256, 0, stream>>>(x, xpad);
    dim3 wtb(32, 8);
    k_wt<<<dim3(16, 128), wtb, 0, stream>>>(W[0], W1t, 396, 512, 4096);
    k_wt<<<dim3(128, 64), wtb, 0, stream>>>(W[1], W2t, 4096, 4096, 2048);
    k_wt<<<dim3(64, 32), wtb, 0, stream>>>(W[2], W3t, 2048, 2048, 1024);
    k_wt<<<dim3(32, 32), wtb, 0, stream>>>(W[3], W4t, 1024, 1024, 1024);
    k_wt<<<dim3(32, 64), wtb, 0, stream>>>(W[4], W5t, 1024, 1024, 2048);
    k_wt<<<dim3(64, 8), wtb, 0, stream>>>(W[5], W6t, 2048, 2048, 256);

    auto gemm256 = [&](const u16* A, const u16* Wt, const float* bias, u16* Cp,
                       float* st1, float* st2, int K, int N, int fuse) {
        int bx = N / 256;
        k_gemm256<<<bx * (NN / 256), 512, 131072, stream>>>(A, Wt, bias, Cp, st1, st2, K, N, bx, fuse);
    };
    auto agg = [&](const u16* in, u16* o, const float* bias, int li, float* svw,
                   int F, int mode) {
        const float* gp = (mode == 2) ? g[li] : nullptr;
        const float* bep = (mode == 2) ? be[li] : nullptr;
        if (F >= 512) k_agg<8><<<NN, F / 8, 0, stream>>>(in, o, rowptr, csr_src, csr_w, dinv, svec, bias, s1, s2, gp, bep, svw, F, mode);
        else k_agg<4><<<NN, F / 4, 0, stream>>>(in, o, rowptr, csr_src, csr_w, dinv, svec, bias, s1, s2, gp, bep, svw, F, mode);
    };
    auto stats = [&](const u16* h, int F) {
        hipMemsetAsync(s1, 0, 2 * 4096 * sizeof(float), stream);   // s1+s2 (contiguous)
        if (F >= 512) k_stats<8><<<dim3(1, NN / SROWS), F / 8, 0, stream>>>(h, s1, s2, F);
        else k_stats<4><<<dim3(1, NN / SROWS), F / 4, 0, stream>>>(h, s1, s2, F);
    };
    auto bnapply = [&](u16* h, int F, int li) {
        k_bnapply<<<(int)(((size_t)NN * F / 8) / 256), 256, 0, stream>>>(h, s1, s2, g[li], be[li], F);
    };

    // --- L1: 396(512) -> 4096, agg-first (writes svec); stats fused; BN1 applied ---
    agg(xpad, Bbuf, nullptr, 0, svec, 512, 0);
    hipMemsetAsync(s1, 0, 2 * 4096 * sizeof(float), stream);
    gemm256(Bbuf, W1t, bv[0], Abuf, s1, s2, 512, 4096, 1);
    bnapply(Abuf, 4096, 0);

    // --- L2: 4096 -> 2048, gemm-first; BN2 applied ---
    gemm256(Abuf, W2t, nullptr, Bbuf, nullptr, nullptr, 4096, 2048, 0);
    agg(Bbuf, Abuf, bv[1], 1, nullptr, 2048, 1);
    stats(Abuf, 2048);
    bnapply(Abuf, 2048, 1);

    // --- L3: 2048 -> 1024, gemm-first; BN3 applied ---
    gemm256(Abuf, W3t, nullptr, Bbuf, nullptr, nullptr, 2048, 1024, 0);
    agg(Bbuf, Abuf, bv[2], 2, nullptr, 1024, 1);
    stats(Abuf, 1024);
    bnapply(Abuf, 1024, 2);

    // --- L4: 1024 -> 1024, gemm-first; BN4 unapplied (inline-folded into L5 agg) ---
    gemm256(Abuf, W4t, nullptr, Bbuf, nullptr, nullptr, 1024, 1024, 0);
    agg(Bbuf, Abuf, bv[3], 3, nullptr, 1024, 1);
    stats(Abuf, 1024);                                      // BN4 stats -> s1,s2

    // --- L5: 1024 -> 2048, agg-first, BN4 a,b inline (mode 2); stats fused; BN5 applied ---
    agg(Abuf, Bbuf, nullptr, 3, nullptr, 1024, 2);
    hipMemsetAsync(s1, 0, 2 * 4096 * sizeof(float), stream);
    gemm256(Bbuf, W5t, bv[4], Abuf, s1, s2, 1024, 2048, 1);
    bnapply(Abuf, 2048, 4);

    // --- L6: 2048 -> 256 (128^2 GEMM); BN6 unapplied (inline-folded into GEMV) ---
    k_gemm<<<(256 / 128) * (NN / 128), 256, 0, stream>>>(Abuf, W6t, nullptr, Bbuf, 2048, 256, 256 / 128, 0);
    agg(Bbuf, Abuf, bv[5], 5, nullptr, 256, 1);
    stats(Abuf, 256);                                       // BN6 stats -> s1,s2

    // --- L7: 256 -> 1 with BN6 inline in GEMV, then agg + pool ---
    k_gemv<<<NN / 4, 256, 0, stream>>>(Abuf, W[6], s1, s2, g[5], be[5], y);
    hipMemsetAsync(d_out, 0, NG * sizeof(float), stream);
    k_final<<<NN / 256, 256, 0, stream>>>(y, rowptr, csr_src, csr_w, dinv, batch, bv[6], out);
}

// Round 18
// 1367.353 us; speedup vs baseline: 1.0362x; 1.0279x over previous
//
#include <hip/hip_runtime.h>

// GCN: 7x GCNConv (first 6 with ReLU+BN training-mode), then global_add_pool.
// N=16384 nodes, E=131072 edges, 64 graphs. fp32 in/out, fp16 internal + MFMA.
// agg on the narrow side per layer (agg is linear).
// BN: W-fold abandoned (R4/R11). Exact mode-2 folds (a*agg(h)+s_i*b, fp32 regs):
//   BN3 -> L4 agg, BN4 -> L5 agg, BN6 -> GEMV. Explicit bnapply only for
//   BN1/BN2/BN5. Stats fused into GEMM epilogue for L1/L4/L5 (dual stat bufs).
// GEMM: 256x256, rotation swizzle (conflicts=0), TWO barriers per K-tile,
// 32-MFMA clusters (R14/R17-measured best: 245us/1122TF on L2 shape).

#define NN 16384
#define NE 131072
#define NG 64

typedef unsigned int u32;
typedef unsigned short u16;
typedef __attribute__((ext_vector_type(8))) _Float16 half8;
typedef __attribute__((ext_vector_type(4))) float f32x4;
typedef __attribute__((ext_vector_type(8))) u16 us8;
typedef __attribute__((ext_vector_type(4))) u16 us4;
typedef __attribute__((ext_vector_type(2))) u16 us2;

#define AS1(p) ((const __attribute__((address_space(1))) void*)(p))
#define AS3(p) ((__attribute__((address_space(3))) void*)(p))

__device__ __forceinline__ float b2f(u16 h) {
    _Float16 x = __builtin_bit_cast(_Float16, h);
    return (float)x;
}
__device__ __forceinline__ u16 f2b(float f) {
    _Float16 x = (_Float16)f;
    return __builtin_bit_cast(u16, x);
}

template <int VW> struct VecU;
template <> struct VecU<8> { typedef us8 T; };
template <> struct VecU<4> { typedef us4 T; };
template <> struct VecU<2> { typedef us2 T; };
template <> struct VecU<1> { typedef u16 T; };

template <int VW>
__device__ __forceinline__ void loadf(const u16* p, float* f) {
    typename VecU<VW>::T v = *(const typename VecU<VW>::T*)p;
    if constexpr (VW == 1) {
        f[0] = b2f((u16)v);
    } else {
        #pragma unroll
        for (int j = 0; j < VW; ++j) f[j] = b2f(v[j]);
    }
}
template <int VW>
__device__ __forceinline__ void storef(u16* p, const float* f) {
    typename VecU<VW>::T v;
    if constexpr (VW == 1) {
        v = f2b(f[0]);
    } else {
        #pragma unroll
        for (int j = 0; j < VW; ++j) v[j] = f2b(f[j]);
    }
    *(typename VecU<VW>::T*)p = v;
}

// BN affine from stats: a = g*rsqrt(var+eps), b = be - m*a
__device__ __forceinline__ void bn_ab(float s1c, float s2c, float gc, float bec,
                                      float& a, float& b) {
    float m = s1c * (1.f / NN);
    float var = s2c * (1.f / NN) - m * m;
    a = gc * rsqrtf(var + 1e-5f);
    b = bec - m * a;
}

// ---------- graph prep ----------
__global__ void k_degi(const int* __restrict__ dst, int* __restrict__ deg) {
    int e = blockIdx.x * 256 + threadIdx.x;
    if (e < NE) atomicAdd(&deg[dst[e]], 1);
}
// scan over degrees -> rowptr; also writes dinv = rsqrt(deg+1)
__global__ __launch_bounds__(1024) void k_scan(const int* __restrict__ deg, int* __restrict__ rowptr,
                                               float* __restrict__ dinv) {
    __shared__ int part[1024];
    int t = threadIdx.x;
    int base = t * 16;
    int s = 0;
    #pragma unroll
    for (int j = 0; j < 16; ++j) {
        int d = deg[base + j];
        dinv[base + j] = rsqrtf((float)(d + 1));   // +1 self loop
        s += d;
    }
    part[t] = s;
    __syncthreads();
    for (int off = 1; off < 1024; off <<= 1) {
        int v = 0;
        if (t >= off) v = part[t - off];
        __syncthreads();
        part[t] += v;
        __syncthreads();
    }
    int run = part[t] - s;  // exclusive prefix
    for (int j = 0; j < 16; ++j) { rowptr[base + j] = run; run += deg[base + j]; }
    if (t == 1023) rowptr[NN] = run;
}
// place edges into CSR; edge weight computed inline (nrm buffer/kernel removed)
__global__ void k_place(const int* __restrict__ src, const int* __restrict__ dst,
                        const float* __restrict__ dinv, const int* __restrict__ rowptr,
                        int* __restrict__ cursor, int* __restrict__ csr_src,
                        float* __restrict__ csr_w) {
    int e = blockIdx.x * 256 + threadIdx.x;
    if (e >= NE) return;
    int sidx = src[e];
    int d = dst[e];
    int p = rowptr[d] + atomicAdd(&cursor[d], 1);
    csr_src[p] = sidx;
    csr_w[p] = dinv[sidx] * dinv[d];
}

// ---------- conversions ----------
// x (NN x 396 f32) -> xpad (NN x 512 f16), vectorized us8 stores
__global__ void k_x2b(const float* __restrict__ x, u16* __restrict__ xp) {
    int idx = blockIdx.x * 256 + threadIdx.x;   // over NN*64
    int i = idx >> 6, cg = idx & 63;
    int c0 = cg * 8;
    float v[8];
    #pragma unroll
    for (int j = 0; j < 8; ++j) {
        int c = c0 + j;
        v[j] = (c < 396) ? x[(size_t)i * 396 + c] : 0.f;
    }
    storef<8>(xp + (size_t)i * 512 + c0, v);
}
// Wt[n][k] = f16(W[k][n]), K padded with zeros
__global__ void k_wt(const float* __restrict__ W, u16* __restrict__ Wt,
                     int Ksrc, int Kpad, int N) {
    __shared__ float t[32][33];
    int k0 = blockIdx.x * 32, n0 = blockIdx.y * 32;
    int tx = threadIdx.x, ty = threadIdx.y;
    #pragma unroll
    for (int j = 0; j < 4; ++j) {
        int k = k0 + ty + j * 8;
        float v = 0.f;
        if (k < Ksrc) v = W[(size_t)k * N + n0 + tx];
        t[ty + j * 8][tx] = v;
    }
    __syncthreads();
    #pragma unroll
    for (int j = 0; j < 4; ++j) {
        int n = n0 + ty + j * 8;
        int k = k0 + tx;
        Wt[(size_t)n * Kpad + k] = f2b(t[tx][ty + j * 8]);
    }
}

// ---------- CSR gather aggregation (one block per node, F/VW threads) ----------
// mode 0: out = acc
// mode 1: out = relu(acc + bias[c])
// mode 2: out = a[c]*acc + s_i*b[c], a,b inline from st1/st2/g/be (exact fold)
// svw non-null: thread 0 also writes svec[i] = dinv_i^2 + sum(w) (agg row-sum).
template <int VW>
__global__ __launch_bounds__(256) void k_agg(const u16* __restrict__ in, u16* __restrict__ out,
                                             const int* __restrict__ rowptr,
                                             const int* __restrict__ csr_src,
                                             const float* __restrict__ csr_w,
                                             const float* __restrict__ dinv,
                                             const float* __restrict__ svec,
                                             const float* __restrict__ bias,
                                             const float* __restrict__ st1,
                                             const float* __restrict__ st2,
                                             const float* __restrict__ g,
                                             const float* __restrict__ be,
                                             float* __restrict__ svw,
                                             int F, int mode) {
    int i = blockIdx.x;
    int c0 = threadIdx.x * VW;
    float acc[VW];
    float d2 = dinv[i]; d2 *= d2;
    float wsum = d2;
    {
        float v[VW];
        loadf<VW>(in + (size_t)i * F + c0, v);
        #pragma unroll
        for (int j = 0; j < VW; ++j) acc[j] = d2 * v[j];
    }
    int r0 = rowptr[i], r1 = rowptr[i + 1];
    int e = r0;
    if (r1 - r0 >= 2) {                 // dual-accumulator ILP
        float acc2[VW];
        #pragma unroll
        for (int j = 0; j < VW; ++j) acc2[j] = 0.f;
        for (; e + 1 < r1; e += 2) {
            int sa = csr_src[e], sb = csr_src[e + 1];
            float wa = csr_w[e], wb = csr_w[e + 1];
            wsum += wa + wb;
            float va[VW], vb[VW];
            loadf<VW>(in + (size_t)sa * F + c0, va);
            loadf<VW>(in + (size_t)sb * F + c0, vb);
            #pragma unroll
            for (int j = 0; j < VW; ++j) { acc[j] += wa * va[j]; acc2[j] += wb * vb[j]; }
        }
        #pragma unroll
        for (int j = 0; j < VW; ++j) acc[j] += acc2[j];
    }
    for (; e < r1; ++e) {
        int s = csr_src[e];
        float w = csr_w[e];
        wsum += w;
        float v[VW];
        loadf<VW>(in + (size_t)s * F + c0, v);
        #pragma unroll
        for (int j = 0; j < VW; ++j) acc[j] += w * v[j];
    }
    if (mode == 1) {
        #pragma unroll
        for (int j = 0; j < VW; ++j) acc[j] = fmaxf(acc[j] + bias[c0 + j], 0.f);
    } else if (mode == 2) {
        float si = svec[i];
        #pragma unroll
        for (int j = 0; j < VW; ++j) {
            float a, b;
            bn_ab(st1[c0 + j], st2[c0 + j], g[c0 + j], be[c0 + j], a, b);
            acc[j] = a * acc[j] + si * b;
        }
    }
    storef<VW>(out + (size_t)i * F + c0, acc);
    if (svw && threadIdx.x == 0) svw[i] = wsum;
}

// ---------- BN stats (for agg-output layers); block = F/VW threads ----------
#define SROWS 128
template <int VW>
__global__ __launch_bounds__(256) void k_stats(const u16* __restrict__ h, float* __restrict__ s1,
                                               float* __restrict__ s2, int F) {
    int c0 = threadIdx.x * VW;
    int r0 = blockIdx.y * SROWS;
    float s[VW], q[VW];
    #pragma unroll
    for (int j = 0; j < VW; ++j) { s[j] = 0.f; q[j] = 0.f; }
    for (int r = r0; r < r0 + SROWS; ++r) {
        float v[VW];
        loadf<VW>(h + (size_t)r * F + c0, v);
        #pragma unroll
        for (int j = 0; j < VW; ++j) { s[j] += v[j]; q[j] += v[j] * v[j]; }
    }
    #pragma unroll
    for (int j = 0; j < VW; ++j) {
        atomicAdd(&s1[c0 + j], s[j]);
        atomicAdd(&s2[c0 + j], q[j]);
    }
}
// fused stats->affine apply: h = a*(h-m)+be, a,b computed per-thread from s1/s2
__global__ __launch_bounds__(256) void k_bnapply(u16* __restrict__ h, const float* __restrict__ s1,
                                                 const float* __restrict__ s2,
                                                 const float* __restrict__ g,
                                                 const float* __restrict__ be, int F) {
    size_t idx = blockIdx.x * (size_t)256 + threadIdx.x;
    int Fv = F >> 3;
    int c = (int)(idx % Fv) * 8;
    u16* p = h + idx * 8;
    float v[8];
    loadf<8>(p, v);
    #pragma unroll
    for (int j = 0; j < 8; ++j) {
        float a, b;
        bn_ab(s1[c + j], s2[c + j], g[c + j], be[c + j], a, b);
        v[j] = a * v[j] + b;
    }
    storef<8>(p, v);
}

// ================= 256x256 MFMA GEMM (f16), 2 barriers per K-tile =================
// C[M,N] = A[M,K] @ Wt[N,K]^T. 512 thr = 8 waves (2 Mx4 N), BK=64,
// LDS 128 KiB: A[2buf][2Khalf][16KiB] @0, B same @64KiB.
// Rotation perm (conflict-free): granule c of row r at LDS granule (c+(r>>1))&3.
// Per kt: ph0 {read kk=0 both mh (12 b128), stage h1(kt+1) A+B, 32 MFMA} BAR
//         ph1 {read kk=1 both mh, stage h0(kt+2) A+B, 32 MFMA, vmcnt(4)} BAR
__device__ __forceinline__ void stage16k(const char* gbase, size_t rs, int ktile, int h,
                                         char* slot, int tid) {
    size_t colb = (size_t)ktile * 128 + h * 64;
    #pragma unroll
    for (int i = 0; i < 2; ++i) {
        int G = i * 512 + tid;
        int r = G >> 2;
        int c = ((G & 3) - (r >> 1)) & 3;   // inverse of storage rotation
        __builtin_amdgcn_global_load_lds(AS1(gbase + (size_t)r * rs + colb + c * 16),
                                         AS3(slot + i * 8192 + ((tid >> 6) << 10)), 16, 0, 0);
    }
}

__global__ __launch_bounds__(512, 2) void k_gemm256(const u16* __restrict__ A,
                                                    const u16* __restrict__ Wt,
                                                    const float* __restrict__ bias,
                                                    u16* __restrict__ C,
                                                    float* __restrict__ s1,
                                                    float* __restrict__ s2,
                                                    int K, int N, int bx, int fuse) {
    extern __shared__ __align__(16) char smem[];
    int nwg = gridDim.x;
    int chunk = nwg >> 3;
    int swz = (blockIdx.x & 7) * chunk + (blockIdx.x >> 3);
    int tx = swz % bx, ty = swz / bx;
    int tid = threadIdx.x;
    int wid = tid >> 6, lane = tid & 63;
    int wr = wid >> 2, wc = wid & 3;         // 2 x 4 wave grid
    int lo = lane & 15, hi = lane >> 4;
    int sw = (((hi + (lo >> 1)) & 3) << 4);  // rotation swizzle (conflict-free)
    size_t row0 = (size_t)ty * 256;
    size_t col0 = (size_t)tx * 256;
    int nkt = K >> 6;

    const char* gA = (const char*)(A + row0 * K);
    const char* gB = (const char*)(Wt + col0 * K);
    size_t rs = (size_t)K * 2;

    const char* aA = smem + wr * 8192 + lo * 64 + sw;
    const char* bA = smem + 65536 + wc * 4096 + lo * 64 + sw;
#define ASL(b, h) (smem + (((b) * 2 + (h)) << 14))
#define BSL(b, h) (smem + 65536 + (((b) * 2 + (h)) << 14))

    f32x4 acc[8][4];
    #pragma unroll
    for (int m = 0; m < 8; ++m)
        #pragma unroll
        for (int n = 0; n < 4; ++n) acc[m][n] = {0.f, 0.f, 0.f, 0.f};
    half8 af0[4], af1[4], bf[4];

    // ---- prologue: kt0 fully + kt1 h0 ----
    stage16k(gA, rs, 0, 0, ASL(0, 0), tid);
    stage16k(gB, rs, 0, 0, BSL(0, 0), tid);
    stage16k(gA, rs, 0, 1, ASL(0, 1), tid);
    stage16k(gB, rs, 0, 1, BSL(0, 1), tid);
    stage16k(gA, rs, 1, 0, ASL(1, 0), tid);
    stage16k(gB, rs, 1, 0, BSL(1, 0), tid);
    asm volatile("s_waitcnt vmcnt(4)" ::: "memory");
    __builtin_amdgcn_sched_barrier(0);
    __builtin_amdgcn_s_barrier();

#define DS_LOADS2(KK)                                                                      \
    {                                                                                      \
        _Pragma("unroll") for (int j = 0; j < 4; ++j)                                      \
            af0[j] = *(const half8*)(aA + buf * 32768 + (KK) * 16384 + j * 1024);          \
        _Pragma("unroll") for (int j = 0; j < 4; ++j)                                      \
            af1[j] = *(const half8*)(aA + buf * 32768 + (KK) * 16384 + 4096 + j * 1024);   \
        _Pragma("unroll") for (int j = 0; j < 4; ++j)                                      \
            bf[j] = *(const half8*)(bA + buf * 32768 + (KK) * 16384 + j * 1024);           \
    }
#define MFMA_BOTH                                                                          \
    {                                                                                      \
        __builtin_amdgcn_s_setprio(1);                                                     \
        _Pragma("unroll") for (int j = 0; j < 4; ++j)                                      \
            _Pragma("unroll") for (int n = 0; n < 4; ++n)                                  \
                acc[j][n] = __builtin_amdgcn_mfma_f32_16x16x32_f16(                        \
                    af0[j], bf[n], acc[j][n], 0, 0, 0);                                    \
        _Pragma("unroll") for (int j = 0; j < 4; ++j)                                      \
            _Pragma("unroll") for (int n = 0; n < 4; ++n)                                  \
                acc[4 + j][n] = __builtin_amdgcn_mfma_f32_16x16x32_f16(                    \
                    af1[j], bf[n], acc[4 + j][n], 0, 0, 0);                                \
        __builtin_amdgcn_s_setprio(0);                                                     \
    }
#define END_BARRIER                                                                        \
    {                                                                                      \
        asm volatile("" ::: "memory");                                                     \
        __builtin_amdgcn_s_barrier();                                                      \
    }

    for (int kt = 0; kt < nkt; ++kt) {
        int buf = kt & 1;
        // ph0: kk=0, all 8 fm ; stage h1(kt+1) -> buf^1
        DS_LOADS2(0);
        if (kt + 1 < nkt) {
            stage16k(gA, rs, kt + 1, 1, ASL(buf ^ 1, 1), tid);
            stage16k(gB, rs, kt + 1, 1, BSL(buf ^ 1, 1), tid);
        }
        MFMA_BOTH;
        END_BARRIER;
        // ph1: kk=1, all 8 fm ; stage h0(kt+2) -> buf ; counted vmcnt
        DS_LOADS2(1);
        if (kt + 2 < nkt) {
            stage16k(gA, rs, kt + 2, 0, ASL(buf, 0), tid);
            stage16k(gB, rs, kt + 2, 0, BSL(buf, 0), tid);
        }
        MFMA_BOTH;
        asm volatile("s_waitcnt vmcnt(4)" ::: "memory");
        __builtin_amdgcn_sched_barrier(0);
        END_BARRIER;
    }

    // ---- epilogue (+ optional fused column stats) ----
    float cs[4] = {0.f, 0.f, 0.f, 0.f}, cq[4] = {0.f, 0.f, 0.f, 0.f};
    #pragma unroll
    for (int fm = 0; fm < 8; ++fm) {
        #pragma unroll
        for (int n = 0; n < 4; ++n) {
            #pragma unroll
            for (int r = 0; r < 4; ++r) {
                size_t row = row0 + wr * 128 + fm * 16 + hi * 4 + r;
                size_t col = col0 + wc * 64 + n * 16 + lo;
                float v = acc[fm][n][r];
                if (fuse) v = fmaxf(v + bias[col], 0.f);
                C[row * N + col] = f2b(v);
                cs[n] += v;
                cq[n] += v * v;
            }
        }
    }
    if (s1) {
        asm volatile("s_waitcnt vmcnt(0)" ::: "memory");
        __syncthreads();
        float* sp = (float*)smem;        // 512 floats: [localcol][0]=sum,[1]=sumsq
        sp[tid] = 0.f;
        __syncthreads();
        #pragma unroll
        for (int n = 0; n < 4; ++n) {
            int lc = wc * 64 + n * 16 + lo;
            atomicAdd(&sp[lc * 2], cs[n]);
            atomicAdd(&sp[lc * 2 + 1], cq[n]);
        }
        __syncthreads();
        if (tid < 256) {
            atomicAdd(&s1[col0 + tid], sp[tid * 2]);
            atomicAdd(&s2[col0 + tid], sp[tid * 2 + 1]);
        }
    }
#undef DS_LOADS2
#undef MFMA_BOTH
#undef END_BARRIER
#undef ASL
#undef BSL
}

// ---------- 128x128 m97-style GEMM (kept for N=256 layer) ----------
__global__ __launch_bounds__(256) void k_gemm(const u16* __restrict__ A, const u16* __restrict__ Wt,
                                              const float* __restrict__ bias, u16* __restrict__ C,
                                              int K, int N, int bx, int fuse) {
    __shared__ __align__(16) u16 As[128 * 32];
    __shared__ __align__(16) u16 Bs[128 * 32];
    int nwg = gridDim.x;
    int chunk = nwg >> 3;
    int swz = (blockIdx.x & 7) * chunk + (blockIdx.x >> 3);
    int tx = swz % bx, ty = swz / bx;
    int tid = threadIdx.x;
    int wid = tid >> 6, lane = tid & 63;
    int wr = wid >> 1, wc = wid & 1;
    int lo = lane & 15, hi = lane >> 4;
    size_t row0 = (size_t)ty * 128;
    size_t col0 = (size_t)tx * 128;

    f32x4 acc[4][4];
    #pragma unroll
    for (int m = 0; m < 4; ++m)
        #pragma unroll
        for (int n = 0; n < 4; ++n) acc[m][n] = {0.f, 0.f, 0.f, 0.f};

    const char* gA = (const char*)(A + row0 * K);
    const char* gB = (const char*)(Wt + col0 * K);
    size_t rs = (size_t)K * 2;
    int lin0 = tid * 16;
    int lin1 = lin0 + 4096;
    int rA0 = lin0 >> 6, cb0 = lin0 & 63;
    int rA1 = lin1 >> 6, cb1 = lin1 & 63;
    unsigned ldsOff = (unsigned)(wid << 10);

    for (int k0 = 0; k0 < K; k0 += 32) {
        __syncthreads();
        size_t kb = (size_t)k0 * 2;
        __builtin_amdgcn_global_load_lds(AS1(gA + (size_t)rA0 * rs + cb0 + kb),
                                         AS3((char*)As + ldsOff), 16, 0, 0);
        __builtin_amdgcn_global_load_lds(AS1(gA + (size_t)rA1 * rs + cb1 + kb),
                                         AS3((char*)As + 4096 + ldsOff), 16, 0, 0);
        __builtin_amdgcn_global_load_lds(AS1(gB + (size_t)rA0 * rs + cb0 + kb),
                                         AS3((char*)Bs + ldsOff), 16, 0, 0);
        __builtin_amdgcn_global_load_lds(AS1(gB + (size_t)rA1 * rs + cb1 + kb),
                                         AS3((char*)Bs + 4096 + ldsOff), 16, 0, 0);
        __syncthreads();
        half8 afr[4], bfr[4];
        #pragma unroll
        for (int m = 0; m < 4; ++m)
            afr[m] = *(const half8*)((const u16*)As + (wr * 64 + m * 16 + lo) * 32 + hi * 8);
        #pragma unroll
        for (int n = 0; n < 4; ++n)
            bfr[n] = *(const half8*)((const u16*)Bs + (wc * 64 + n * 16 + lo) * 32 + hi * 8);
        #pragma unroll
        for (int m = 0; m < 4; ++m)
            #pragma unroll
            for (int n = 0; n < 4; ++n)
                acc[m][n] = __builtin_amdgcn_mfma_f32_16x16x32_f16(afr[m], bfr[n], acc[m][n], 0, 0, 0);
    }
    #pragma unroll
    for (int m = 0; m < 4; ++m) {
        #pragma unroll
        for (int n = 0; n < 4; ++n) {
            #pragma unroll
            for (int r = 0; r < 4; ++r) {
                size_t row = row0 + wr * 64 + m * 16 + hi * 4 + r;
                size_t col = col0 + wc * 64 + n * 16 + lo;
                float v = acc[m][n][r];
                if (fuse) v = fmaxf(v + bias[col], 0.f);
                C[row * N + col] = f2b(v);
            }
        }
    }
}

// ---------- layer 7: fused BN6 + GEMV (a,b inline from s1/s2) ----------
__global__ __launch_bounds__(256) void k_gemv(const u16* __restrict__ A, const float* __restrict__ w,
                                              const float* __restrict__ s1, const float* __restrict__ s2,
                                              const float* __restrict__ g, const float* __restrict__ be,
                                              float* __restrict__ y) {
    int row = blockIdx.x * 4 + (threadIdx.x >> 6);
    int lane = threadIdx.x & 63;
    const u16* h = A + (size_t)row * 256;
    float s = 0.f;
    #pragma unroll
    for (int j = 0; j < 4; ++j) {
        int c = lane + j * 64;
        float a, b;
        bn_ab(s1[c], s2[c], g[c], be[c], a, b);
        s += (a * b2f(h[c]) + b) * w[c];
    }
    #pragma unroll
    for (int off = 32; off; off >>= 1) s += __shfl_down(s, off);
    if (lane == 0) y[row] = s;
}
__global__ void k_final(const float* __restrict__ y, const int* __restrict__ rowptr,
                        const int* __restrict__ csr_src, const float* __restrict__ csr_w,
                        const float* __restrict__ dinv, const int* __restrict__ batch,
                        const float* __restrict__ b7, float* __restrict__ out) {
    int i = blockIdx.x * 256 + threadIdx.x;
    if (i >= NN) return;
    float v = dinv[i] * dinv[i] * y[i];
    int r1 = rowptr[i + 1];
    for (int e = rowptr[i]; e < r1; ++e) v += csr_w[e] * y[csr_src[e]];
    atomicAdd(&out[batch[i]], v + b7[0]);
}
__global__ void k_sentinel(float* out, float v) {
    if (threadIdx.x == 0 && blockIdx.x == 0) out[0] = v;
}

// ---------- host ----------
static inline char* alignp(char* p) { return (char*)(((uintptr_t)p + 255) & ~(uintptr_t)255); }

extern "C" void kernel_launch(void* const* d_in, const int* in_sizes, int n_in,
                              void* d_out, int out_size, void* d_ws, size_t ws_size,
                              hipStream_t stream) {
    const float* x = (const float*)d_in[0];
    const int* ei = (const int*)d_in[1];
    const int* src = ei;
    const int* dst = ei + NE;
    const int* batch = (const int*)d_in[2];
    const float* W[7]; const float* bv[7];
    for (int i = 0; i < 7; ++i) { W[i] = (const float*)d_in[3 + 2 * i]; bv[i] = (const float*)d_in[4 + 2 * i]; }
    const float* g[6]; const float* be[6];
    for (int i = 0; i < 6; ++i) { g[i] = (const float*)d_in[17 + 2 * i]; be[i] = (const float*)d_in[18 + 2 * i]; }
    float* out = (float*)d_out;

    // workspace layout
    char* p = (char*)d_ws;
    u16* Abuf = (u16*)p; p += (size_t)NN * 4096 * 2;
    u16* Bbuf = (u16*)p; p += (size_t)NN * 2048 * 2;
    u16* xpad = (u16*)p; p += (size_t)NN * 512 * 2;
    u16* W1t = (u16*)p; p += (size_t)4096 * 512 * 2;
    u16* W2t = (u16*)p; p += (size_t)2048 * 4096 * 2;
    u16* W3t = (u16*)p; p += (size_t)1024 * 2048 * 2;
    u16* W4t = (u16*)p; p += (size_t)1024 * 1024 * 2;
    u16* W5t = (u16*)p; p += (size_t)2048 * 1024 * 2;
    u16* W6t = (u16*)p; p += (size_t)256 * 2048 * 2;
    p = alignp(p);
    int* degi = (int*)p; p += NN * 4;
    int* cursor = (int*)p; p += NN * 4;
    int* rowptr = (int*)p; p += (NN + 1) * 4; p = alignp(p);
    int* csr_src = (int*)p; p += NE * 4;
    float* csr_w = (float*)p; p += NE * 4;
    float* dinv = (float*)p; p += NN * 4;
    float* svec = (float*)p; p += NN * 4;
    float* s1 = (float*)p; p += 4096 * 4;
    float* s2 = (float*)p; p += 4096 * 4;
    float* s1b = (float*)p; p += 4096 * 4;
    float* s2b = (float*)p; p += 4096 * 4;
    float* y = (float*)p; p += NN * 4;
    size_t need = (size_t)(p - (char*)d_ws);
    if (need > ws_size) {
        hipMemsetAsync(d_out, 0, NG * sizeof(float), stream);
        k_sentinel<<<1, 64, 0, stream>>>(out, (float)(ws_size >> 20));
        return;
    }

    (void)hipFuncSetAttribute((const void*)k_gemm256,
                              hipFuncAttributeMaxDynamicSharedMemorySize, 131072);

    // --- graph prep ---
    hipMemsetAsync(degi, 0, 2 * NN * sizeof(int), stream);  // degi + cursor
    k_degi<<<NE / 256, 256, 0, stream>>>(dst, degi);
    k_scan<<<1, 1024, 0, stream>>>(degi, rowptr, dinv);     // rowptr + dinv
    k_place<<<NE / 256, 256, 0, stream>>>(src, dst, dinv, rowptr, cursor, csr_src, csr_w);

    // --- conversions (all weights plain f16 transpose) ---
    k_x2b<<<(NN * 64) / 256, 256, 0, stream>>>(x, xpad);
    dim3 wtb(32, 8);
    k_wt<<<dim3(16, 128), wtb, 0, stream>>>(W[0], W1t, 396, 512, 4096);
    k_wt<<<dim3(128, 64), wtb, 0, stream>>>(W[1], W2t, 4096, 4096, 2048);
    k_wt<<<dim3(64, 32), wtb, 0, stream>>>(W[2], W3t, 2048, 2048, 1024);
    k_wt<<<dim3(32, 32), wtb, 0, stream>>>(W[3], W4t, 1024, 1024, 1024);
    k_wt<<<dim3(32, 64), wtb, 0, stream>>>(W[4], W5t, 1024, 1024, 2048);
    k_wt<<<dim3(64, 8), wtb, 0, stream>>>(W[5], W6t, 2048, 2048, 256);

    auto gemm256 = [&](const u16* A, const u16* Wt, const float* bias, u16* Cp,
                       float* st1, float* st2, int K, int N, int fuse) {
        int bx = N / 256;
        k_gemm256<<<bx * (NN / 256), 512, 131072, stream>>>(A, Wt, bias, Cp, st1, st2, K, N, bx, fuse);
    };
    auto agg = [&](const u16* in, u16* o, const float* bias, int li,
                   const float* st1, const float* st2, float* svw, int F, int mode) {
        const float* gp = (mode == 2) ? g[li] : nullptr;
        const float* bep = (mode == 2) ? be[li] : nullptr;
        if (F >= 512) k_agg<8><<<NN, F / 8, 0, stream>>>(in, o, rowptr, csr_src, csr_w, dinv, svec, bias, st1, st2, gp, bep, svw, F, mode);
        else k_agg<4><<<NN, F / 4, 0, stream>>>(in, o, rowptr, csr_src, csr_w, dinv, svec, bias, st1, st2, gp, bep, svw, F, mode);
    };
    auto stats = [&](const u16* h, int F) {
        hipMemsetAsync(s1, 0, 2 * 4096 * sizeof(float), stream);   // s1+s2 (contiguous)
        if (F >= 512) k_stats<8><<<dim3(1, NN / SROWS), F / 8, 0, stream>>>(h, s1, s2, F);
        else k_stats<4><<<dim3(1, NN / SROWS), F / 4, 0, stream>>>(h, s1, s2, F);
    };
    auto bnapply = [&](u16* h, int F, int li) {
        k_bnapply<<<(int)(((size_t)NN * F / 8) / 256), 256, 0, stream>>>(h, s1, s2, g[li], be[li], F);
    };

    // --- L1: 396(512) -> 4096, agg-first (writes svec); stats fused; BN1 applied ---
    agg(xpad, Bbuf, nullptr, 0, nullptr, nullptr, svec, 512, 0);
    hipMemsetAsync(s1, 0, 2 * 4096 * sizeof(float), stream);
    gemm256(Bbuf, W1t, bv[0], Abuf, s1, s2, 512, 4096, 1);
    bnapply(Abuf, 4096, 0);

    // --- L2: 4096 -> 2048, gemm-first; BN2 applied ---
    gemm256(Abuf, W2t, nullptr, Bbuf, nullptr, nullptr, 4096, 2048, 0);
    agg(Bbuf, Abuf, bv[1], 1, nullptr, nullptr, nullptr, 2048, 1);
    stats(Abuf, 2048);
    bnapply(Abuf, 2048, 1);

    // --- L3: 2048 -> 1024, gemm-first; BN3 stats only (fold into L4 agg) ---
    gemm256(Abuf, W3t, nullptr, Bbuf, nullptr, nullptr, 2048, 1024, 0);
    agg(Bbuf, Abuf, bv[2], 2, nullptr, nullptr, nullptr, 1024, 1);
    stats(Abuf, 1024);                                      // BN3 stats -> s1,s2

    // --- L4: 1024 -> 1024, agg-first, BN3 fold (mode 2); stats fused -> s1b,s2b ---
    agg(Abuf, Bbuf, nullptr, 2, s1, s2, nullptr, 1024, 2);  // a3*agg(h3)+s_i*b3
    hipMemsetAsync(s1b, 0, 2 * 4096 * sizeof(float), stream);
    gemm256(Bbuf, W4t, bv[3], Abuf, s1b, s2b, 1024, 1024, 1);  // h4 raw; BN4 stats

    // --- L5: 1024 -> 2048, agg-first, BN4 fold (mode 2, s1b/s2b); stats fused; BN5 applied ---
    agg(Abuf, Bbuf, nullptr, 3, s1b, s2b, nullptr, 1024, 2);
    hipMemsetAsync(s1, 0, 2 * 4096 * sizeof(float), stream);
    gemm256(Bbuf, W5t, bv[4], Abuf, s1, s2, 1024, 2048, 1);
    bnapply(Abuf, 2048, 4);

    // --- L6: 2048 -> 256 (128^2 GEMM); BN6 stats only (fold into GEMV) ---
    k_gemm<<<(256 / 128) * (NN / 128), 256, 0, stream>>>(Abuf, W6t, nullptr, Bbuf, 2048, 256, 256 / 128, 0);
    agg(Bbuf, Abuf, bv[5], 5, nullptr, nullptr, nullptr, 256, 1);
    stats(Abuf, 256);                                       // BN6 stats -> s1,s2

    // --- L7: 256 -> 1 with BN6 inline in GEMV, then agg + pool ---
    k_gemv<<<NN / 4, 256, 0, stream>>>(Abuf, W[6], s1, s2, g[5], be[5], y);
    hipMemsetAsync(d_out, 0, NG * sizeof(float), stream);
    k_final<<<NN / 256, 256, 0, stream>>>(y, rowptr, csr_src, csr_w, dinv, batch, bv[6], out);
}